// Round 16
// baseline (187.858 us; speedup 1.0000x reference)
//
#include <hip/hip_runtime.h>
#include <hip/hip_bf16.h>

typedef __attribute__((ext_vector_type(8))) short short8;
typedef __attribute__((ext_vector_type(8))) unsigned short u16x8;
typedef __attribute__((ext_vector_type(4))) unsigned short u16x4;
typedef __attribute__((ext_vector_type(4))) float f32x4;
typedef __attribute__((ext_vector_type(4))) unsigned u32x4;

#define NTOK 768
#define ED   768
#define SD   384
#define PD   128
#define NH   16
#define DH   48
#define LGS  778
#define NRIDE 192   // pair rows computed by k_gemm_qkvg rider blocks (register-direct)

__device__ __forceinline__ unsigned short f2bf(float x) {
  unsigned u = __builtin_bit_cast(unsigned, x);
  u += 0x7FFFu + ((u >> 16) & 1u);
  return (unsigned short)(u >> 16);
}
__device__ __forceinline__ float bf2f(unsigned short b) {
  unsigned u = ((unsigned)b) << 16;
  return __builtin_bit_cast(float, u);
}
__device__ __forceinline__ float sigm(float x) { return 1.0f / (1.0f + __expf(-x)); }

__device__ __forceinline__ unsigned cvtpk(float a, float b) {
  unsigned r;
  asm("v_cvt_pk_bf16_f32 %0, %1, %2" : "=v"(r) : "v"(a), "v"(b));
  return r;
}
__device__ __forceinline__ float lo2f(unsigned p) {
  return __builtin_bit_cast(float, p << 16);
}
__device__ __forceinline__ float hi2f(unsigned p) {
  return __builtin_bit_cast(float, p & 0xFFFF0000u);
}

__device__ __forceinline__ void gl2lds(const unsigned short* g, unsigned short* l) {
  __builtin_amdgcn_global_load_lds(
      (const __attribute__((address_space(1))) unsigned int*)g,
      (__attribute__((address_space(3))) unsigned int*)l, 16, 0, 0);
}

// ---------------- workspace layout (bytes) ----------------
constexpr size_t SZ_SN   = (size_t)NTOK * SD * 2;
constexpr size_t OFF_SNH = 0;
constexpr size_t OFF_SNL = OFF_SNH + SZ_SN;
constexpr size_t OFF_SRH = OFF_SNL + SZ_SN;
constexpr size_t OFF_SRL = OFF_SRH + SZ_SN;
constexpr size_t OFF_GAM = OFF_SRL + SZ_SN;                // f32 [768][768]
constexpr size_t OFF_BET = OFF_GAM + 2359296;
constexpr size_t OFF_OG  = OFF_BET + 2359296;
constexpr size_t OFF_AMH = OFF_OG  + 2359296;              // bf16 [768][768]
constexpr size_t OFF_AML = OFF_AMH + 1179648;
constexpr size_t OFF_QB  = OFF_AML + 1179648;
constexpr size_t OFF_KB  = OFF_QB  + 1179648;
constexpr size_t OFF_VT  = OFF_KB  + 1179648;              // bf16 [768 hd][768 m]
constexpr size_t OFF_GBUF= OFF_VT  + 1179648;              // f32
constexpr size_t OFF_AGH = OFF_GBUF+ 2359296;
constexpr size_t OFF_AGL = OFF_AGH + 1179648;
constexpr size_t OFF_WSMH= OFF_AGL + 1179648;              // [2304][384] bf16
constexpr size_t OFF_WSML= OFF_WSMH+ 1769472;
constexpr size_t OFF_WQH = OFF_WSML+ 1769472;              // [3072][768] bf16
constexpr size_t OFF_WQL = OFF_WQH + 4718592;
constexpr size_t OFF_WPH = OFF_WQL + 4718592;              // [768][768] bf16
constexpr size_t OFF_WPL = OFF_WPH + 1179648;
constexpr size_t OFF_GWH = OFF_WPL + 1179648;
constexpr size_t OFF_GWL = OFF_GWH + 4096;
constexpr size_t OFF_SGW = OFF_GWL + 4096;
constexpr size_t OFF_QKL = OFF_SGW + 4096;                 // f32 [768 n][16 h][768 m]
constexpr size_t OFF_PB  = OFF_QKL + 37748736;             // bf16 [16 h][768 n][768 m]
constexpr size_t OFF_BB  = OFF_PB  + 18874368;             // f32 [192 n][16 h][768 m]
constexpr size_t WS_NEED = OFF_BB  + 9437184;

// ---------------- preprocessing: weights + setup + LN(s) ----------------
__global__ __launch_bounds__(256) void k_wcvt(
    const float* __restrict__ wag, const float* __restrict__ wab, const float* __restrict__ wo,
    const float* __restrict__ wq, const float* __restrict__ wk, const float* __restrict__ wv,
    const float* __restrict__ wg, const float* __restrict__ wp,
    const float* __restrict__ lng, const float* __restrict__ lnb,
    const float* __restrict__ wpair, const float* __restrict__ s,
    unsigned short* __restrict__ wsmh, unsigned short* __restrict__ wsml,
    unsigned short* __restrict__ wqh, unsigned short* __restrict__ wql,
    unsigned short* __restrict__ wph, unsigned short* __restrict__ wpl,
    unsigned short* __restrict__ gwh, unsigned short* __restrict__ gwl,
    float* __restrict__ sgw, float* __restrict__ bw,
    unsigned short* __restrict__ snh, unsigned short* __restrict__ snl,
    unsigned short* __restrict__ srh, unsigned short* __restrict__ srl) {
  const int tid = threadIdx.x;
  if (blockIdx.z == 8) {
    const int gid = blockIdx.y * 24 + blockIdx.x;
    if (gid == 192) {
      if (tid < 128) {
        float g = lng[tid];
        for (int hh = 0; hh < 16; ++hh) {
          float gwv = g * wpair[tid * 16 + hh];
          unsigned short hb = f2bf(gwv);
          gwh[tid * 16 + hh] = hb;
          gwl[tid * 16 + hh] = f2bf(gwv - bf2f(hb));
        }
      }
      if (tid < 16) {
        float sv = 0.f, bb = 0.f;
        for (int p = 0; p < 128; ++p) {
          float w = wpair[p * 16 + tid];
          sv += lng[p] * w;
          bb += lnb[p] * w;
        }
        sgw[tid] = sv;
        bw[tid]  = bb;
      }
      return;
    }
    if (gid > 192) return;
    const int n = gid * 4 + (tid >> 6);
    const int lane = tid & 63;
    const float* row = s + (size_t)n * SD;
    float v[6], sum = 0.f, sq = 0.f;
#pragma unroll
    for (int i = 0; i < 6; ++i) { v[i] = row[lane + 64 * i]; sum += v[i]; sq += v[i] * v[i]; }
#pragma unroll
    for (int off = 1; off < 64; off <<= 1) { sum += __shfl_xor(sum, off); sq += __shfl_xor(sq, off); }
    float mu = sum * (1.f / SD);
    float var = sq * (1.f / SD) - mu * mu;
    float rs = rsqrtf(var + 1e-5f);
#pragma unroll
    for (int i = 0; i < 6; ++i) {
      size_t idx = (size_t)n * SD + lane + 64 * i;
      float x = v[i];
      unsigned short xh = f2bf(x);
      srh[idx] = xh; srl[idx] = f2bf(x - bf2f(xh));
      float y = (x - mu) * rs;
      unsigned short yh = f2bf(y);
      snh[idx] = yh; snl[idx] = f2bf(y - bf2f(yh));
    }
    return;
  }
  const int id = blockIdx.z;
  const float* src; int Ksrc; unsigned short *dh, *dl; int n0; int Kd;
  switch (id) {
    case 0: src = wag; Ksrc = 384; dh = wsmh; dl = wsml; n0 = 0;    Kd = 384; break;
    case 1: src = wab; Ksrc = 384; dh = wsmh; dl = wsml; n0 = 768;  Kd = 384; break;
    case 2: src = wo;  Ksrc = 384; dh = wsmh; dl = wsml; n0 = 1536; Kd = 384; break;
    case 3: src = wq;  Ksrc = 768; dh = wqh;  dl = wql;  n0 = 0;    Kd = 768; break;
    case 4: src = wk;  Ksrc = 768; dh = wqh;  dl = wql;  n0 = 768;  Kd = 768; break;
    case 5: src = wv;  Ksrc = 768; dh = wqh;  dl = wql;  n0 = 1536; Kd = 768; break;
    case 6: src = wg;  Ksrc = 768; dh = wqh;  dl = wql;  n0 = 2304; Kd = 768; break;
    default: src = wp; Ksrc = 768; dh = wph;  dl = wpl;  n0 = 0;    Kd = 768; break;
  }
  const int kt = blockIdx.x, ntile = blockIdx.y;
  if (kt * 32 >= Ksrc) return;
  __shared__ float t[32][33];
  const int r = tid >> 3, c4 = (tid & 7) * 4;
  float4 v = *(const float4*)(src + (size_t)(kt * 32 + r) * 768 + ntile * 32 + c4);
  t[r][c4 + 0] = v.x; t[r][c4 + 1] = v.y; t[r][c4 + 2] = v.z; t[r][c4 + 3] = v.w;
  __syncthreads();
  u16x4 hv, lv;
#pragma unroll
  for (int j = 0; j < 4; ++j) {
    float x = t[c4 + j][r];
    unsigned short hb = f2bf(x);
    hv[j] = hb;
    lv[j] = f2bf(x - bf2f(hb));
  }
  size_t drow = (size_t)(n0 + ntile * 32 + r) * Kd + kt * 32 + c4;
  *(u16x4*)(dh + drow) = hv;
  *(u16x4*)(dl + drow) = lv;
}

// ---------------- rider: pair bias for one n-row, registers -> global bb ----------------
__device__ __forceinline__ void pair_bias_rows_to_global(
    int n, const float* __restrict__ pair_rep,
    const unsigned short* __restrict__ gw_hi, const unsigned short* __restrict__ gw_lo,
    const float* __restrict__ sgw, const float* __restrict__ bw,
    float* __restrict__ bb) {
  const int tid = threadIdx.x;
  const int wv = tid >> 6, lane = tid & 63;
  const int l15 = lane & 15, kg = lane >> 4;

#define LOADCH2(X, CH) do {                                                       \
    const float* xp_ = pair_rep + ((size_t)n * NTOK + (CH) * 16 + l15) * PD + kg * 8; \
    _Pragma("unroll")                                                             \
    for (int q_ = 0; q_ < 4; ++q_) {                                              \
      X[q_ * 2]     = *(const float4*)(xp_ + q_ * 32);                            \
      X[q_ * 2 + 1] = *(const float4*)(xp_ + q_ * 32 + 4);                        \
    }                                                                             \
  } while (0)

  float4 Xa[8], Xb[8];
  LOADCH2(Xa, wv);
  LOADCH2(Xb, wv + 4);

  short8 bh[4], bl[4];
#pragma unroll
  for (int ks = 0; ks < 4; ++ks)
#pragma unroll
    for (int j = 0; j < 8; ++j) {
      int p = ks * 32 + kg * 8 + j;
      bh[ks][j] = (short)gw_hi[p * 16 + l15];
      bl[ks][j] = (short)gw_lo[p * 16 + l15];
    }
  float sgv[4], bwv[4];
#pragma unroll
  for (int r = 0; r < 4; ++r) { sgv[r] = sgw[kg * 4 + r]; bwv[r] = bw[kg * 4 + r]; }

#define PROC2(X, CH) do {                                                         \
    float sum_ = 0.f, sq_ = 0.f;                                                  \
    _Pragma("unroll")                                                             \
    for (int q_ = 0; q_ < 8; ++q_) {                                              \
      sum_ += X[q_].x + X[q_].y + X[q_].z + X[q_].w;                              \
      sq_ = fmaf(X[q_].x, X[q_].x, sq_); sq_ = fmaf(X[q_].y, X[q_].y, sq_);       \
      sq_ = fmaf(X[q_].z, X[q_].z, sq_); sq_ = fmaf(X[q_].w, X[q_].w, sq_);       \
    }                                                                             \
    sum_ += __shfl_xor(sum_, 16); sum_ += __shfl_xor(sum_, 32);                   \
    sq_  += __shfl_xor(sq_, 16);  sq_  += __shfl_xor(sq_, 32);                    \
    float mu_ = sum_ * (1.f / 128.f);                                             \
    float rstd_ = rsqrtf(sq_ * (1.f / 128.f) - mu_ * mu_ + 1e-5f);                \
    f32x4 acc_ = {0.f, 0.f, 0.f, 0.f};                                            \
    _Pragma("unroll")                                                             \
    for (int ks_ = 0; ks_ < 4; ++ks_) {                                           \
      float4 u0_ = X[ks_ * 2], u1_ = X[ks_ * 2 + 1];                              \
      unsigned p0_ = cvtpk(u0_.x, u0_.y), p1_ = cvtpk(u0_.z, u0_.w);              \
      unsigned p2_ = cvtpk(u1_.x, u1_.y), p3_ = cvtpk(u1_.z, u1_.w);              \
      float l0_ = u0_.x - lo2f(p0_), l1_ = u0_.y - hi2f(p0_);                     \
      float l2_ = u0_.z - lo2f(p1_), l3_ = u0_.w - hi2f(p1_);                     \
      float l4_ = u1_.x - lo2f(p2_), l5_ = u1_.y - hi2f(p2_);                     \
      float l6_ = u1_.z - lo2f(p3_), l7_ = u1_.w - hi2f(p3_);                     \
      unsigned q0_ = cvtpk(l0_, l1_), q1_ = cvtpk(l2_, l3_);                      \
      unsigned q2_ = cvtpk(l4_, l5_), q3_ = cvtpk(l6_, l7_);                      \
      u32x4 hp_ = {p0_, p1_, p2_, p3_}, lp_ = {q0_, q1_, q2_, q3_};               \
      short8 ah_ = __builtin_bit_cast(short8, hp_);                               \
      short8 al_ = __builtin_bit_cast(short8, lp_);                               \
      acc_ = __builtin_amdgcn_mfma_f32_16x16x32_bf16(bh[ks_], ah_, acc_, 0, 0, 0);\
      acc_ = __builtin_amdgcn_mfma_f32_16x16x32_bf16(bh[ks_], al_, acc_, 0, 0, 0);\
      acc_ = __builtin_amdgcn_mfma_f32_16x16x32_bf16(bl[ks_], ah_, acc_, 0, 0, 0);\
    }                                                                             \
    _Pragma("unroll")                                                             \
    for (int r_ = 0; r_ < 4; ++r_) {                                              \
      float val_ = rstd_ * (acc_[r_] - mu_ * sgv[r_]) + bwv[r_];                  \
      bb[(size_t)n * (NH * NTOK) + (kg * 4 + r_) * NTOK + (CH) * 16 + l15] = val_;\
    }                                                                             \
  } while (0)

  PROC2(Xa, wv +  0); LOADCH2(Xa, wv +  8);
  PROC2(Xb, wv +  4); LOADCH2(Xb, wv + 12);
  PROC2(Xa, wv +  8); LOADCH2(Xa, wv + 16);
  PROC2(Xb, wv + 12); LOADCH2(Xb, wv + 20);
  PROC2(Xa, wv + 16); LOADCH2(Xa, wv + 24);
  PROC2(Xb, wv + 20); LOADCH2(Xb, wv + 28);
  PROC2(Xa, wv + 24); LOADCH2(Xa, wv + 32);
  PROC2(Xb, wv + 28); LOADCH2(Xb, wv + 36);
  PROC2(Xa, wv + 32); LOADCH2(Xa, wv + 40);
  PROC2(Xb, wv + 36); LOADCH2(Xb, wv + 44);
  PROC2(Xa, wv + 40);
  PROC2(Xb, wv + 44);
#undef LOADCH2
#undef PROC2
}

// ---------------- split-bf16 MFMA GEMM core: 64x64 tile, 256 threads ----------------
__device__ __forceinline__ void mfma_core(
    const unsigned short* __restrict__ Ah, const unsigned short* __restrict__ Al,
    const unsigned short* __restrict__ Bh, const unsigned short* __restrict__ Bl,
    int K, int mBase, int nBase, f32x4 acc[2][2]) {
  __shared__ unsigned short lds[2][4][4096];
  const int tid = threadIdx.x;
  const int w = tid >> 6, lane = tid & 63;
  const int l15 = lane & 15, kg = lane >> 4;
  const int wr = w >> 1, wc = w & 1;

  size_t offA[2], offB[2];
  int ldsw[2];
#pragma unroll
  for (int i = 0; i < 2; ++i) {
    int chunk = w * 128 + i * 64 + lane;
    int row = chunk >> 3;
    int slot = (chunk & 7) ^ (row & 7);
    offA[i] = (size_t)(mBase + row) * K + slot * 8;
    offB[i] = (size_t)(nBase + row) * K + slot * 8;
    ldsw[i] = w * 1024 + i * 512;
  }
  auto stage = [&](int b, int k0) {
#pragma unroll
    for (int i = 0; i < 2; ++i) {
      gl2lds(Ah + offA[i] + k0, &lds[b][0][ldsw[i]]);
      gl2lds(Al + offA[i] + k0, &lds[b][1][ldsw[i]]);
      gl2lds(Bh + offB[i] + k0, &lds[b][2][ldsw[i]]);
      gl2lds(Bl + offB[i] + k0, &lds[b][3][ldsw[i]]);
    }
  };

  stage(0, 0);
  int buf = 0;
  for (int k0 = 64; k0 <= K; k0 += 64) {
    __syncthreads();
    if (k0 < K) stage(buf ^ 1, k0);
#pragma unroll
    for (int kk = 0; kk < 2; ++kk) {
      short8 ah[2], al[2], bh4[2], bl4[2];
#pragma unroll
      for (int mi = 0; mi < 2; ++mi) {
        int row = wr * 32 + mi * 16 + l15;
        int kb = kk * 64 + kg * 16;
        int idx = row * 64 + ((kb ^ ((row & 7) << 4)) >> 1);
        ah[mi] = *(const short8*)&lds[buf][0][idx];
        al[mi] = *(const short8*)&lds[buf][1][idx];
      }
#pragma unroll
      for (int ni = 0; ni < 2; ++ni) {
        int row = wc * 32 + ni * 16 + l15;
        int kb = kk * 64 + kg * 16;
        int idx = row * 64 + ((kb ^ ((row & 7) << 4)) >> 1);
        bh4[ni] = *(const short8*)&lds[buf][2][idx];
        bl4[ni] = *(const short8*)&lds[buf][3][idx];
      }
#pragma unroll
      for (int mi = 0; mi < 2; ++mi)
#pragma unroll
        for (int ni = 0; ni < 2; ++ni) {
          acc[mi][ni] = __builtin_amdgcn_mfma_f32_16x16x32_bf16(ah[mi], bh4[ni], acc[mi][ni], 0, 0, 0);
          acc[mi][ni] = __builtin_amdgcn_mfma_f32_16x16x32_bf16(al[mi], bh4[ni], acc[mi][ni], 0, 0, 0);
          acc[mi][ni] = __builtin_amdgcn_mfma_f32_16x16x32_bf16(ah[mi], bl4[ni], acc[mi][ni], 0, 0, 0);
        }
    }
    buf ^= 1;
  }
}

// ---------------- GEMM instances (64x64 tiles, 256-thread blocks) ----------------
__global__ __launch_bounds__(256) void k_gemm_small(
    const unsigned short* __restrict__ snh, const unsigned short* __restrict__ snl,
    const unsigned short* __restrict__ srh, const unsigned short* __restrict__ srl,
    const unsigned short* __restrict__ wsmh, const unsigned short* __restrict__ wsml,
    const float* __restrict__ bo,
    float* __restrict__ gaml, float* __restrict__ betl, float* __restrict__ og) {
  const int nt = blockIdx.x, mt = blockIdx.y;
  const unsigned short* Ah = (nt < 24) ? snh : srh;
  const unsigned short* Al = (nt < 24) ? snl : srl;
  f32x4 acc[2][2];
#pragma unroll
  for (int i = 0; i < 2; ++i)
#pragma unroll
    for (int j = 0; j < 2; ++j) acc[i][j] = (f32x4){0.f, 0.f, 0.f, 0.f};
  mfma_core(Ah, Al, wsmh, wsml, SD, mt * 64, nt * 64, acc);
  const int tid = threadIdx.x;
  const int w = tid >> 6, lane = tid & 63;
  const int l15 = lane & 15, kg = lane >> 4;
  const int wr = w >> 1, wc = w & 1;
#pragma unroll
  for (int mi = 0; mi < 2; ++mi)
#pragma unroll
    for (int ni = 0; ni < 2; ++ni) {
      int col = nt * 64 + wc * 32 + ni * 16 + l15;
#pragma unroll
      for (int r = 0; r < 4; ++r) {
        int row = mt * 64 + wr * 32 + mi * 16 + kg * 4 + r;
        float v = acc[mi][ni][r];
        if (col < 768) gaml[(size_t)row * ED + col] = v;
        else if (col < 1536) betl[(size_t)row * ED + col - 768] = v;
        else og[(size_t)row * ED + col - 1536] = sigm(v + bo[col - 1536]);
      }
    }
}

// qkvg GEMM + register-direct pair riders (no LDS use in rider path)
__global__ __launch_bounds__(256) void k_gemm_qkvg(
    const unsigned short* __restrict__ amh, const unsigned short* __restrict__ aml,
    const unsigned short* __restrict__ wqh, const unsigned short* __restrict__ wql,
    const float* __restrict__ bq,
    const float* __restrict__ pair_rep,
    const unsigned short* __restrict__ gwh, const unsigned short* __restrict__ gwl,
    const float* __restrict__ sgw, const float* __restrict__ bw,
    float* __restrict__ biasBuf,
    unsigned short* __restrict__ qb, unsigned short* __restrict__ kb,
    unsigned short* __restrict__ vT, float* __restrict__ gbuf) {
  const int nt = blockIdx.x, mt = blockIdx.y;
  if (mt >= 12) {                       // rider: rows 0..191, registers -> global
    pair_bias_rows_to_global((mt - 12) * 48 + nt, pair_rep, gwh, gwl, sgw, bw, biasBuf);
    return;
  }
  f32x4 acc[2][2];
#pragma unroll
  for (int i = 0; i < 2; ++i)
#pragma unroll
    for (int j = 0; j < 2; ++j) acc[i][j] = (f32x4){0.f, 0.f, 0.f, 0.f};
  mfma_core(amh, aml, wqh, wql, ED, mt * 64, nt * 64, acc);
  const int tid = threadIdx.x;
  const int w = tid >> 6, lane = tid & 63;
  const int l15 = lane & 15, kg = lane >> 4;
  const int wr = w >> 1, wc = w & 1;
  const int sel = nt / 12;
#pragma unroll
  for (int mi = 0; mi < 2; ++mi)
#pragma unroll
    for (int ni = 0; ni < 2; ++ni) {
      int col = nt * 64 + wc * 32 + ni * 16 + l15;
      int c = col - sel * 768;
#pragma unroll
      for (int r = 0; r < 4; ++r) {
        int row = mt * 64 + wr * 32 + mi * 16 + kg * 4 + r;
        float v = acc[mi][ni][r];
        size_t idx = (size_t)row * ED + c;
        if (sel == 0) qb[idx] = f2bf(v + bq[c]);
        else if (sel == 1) kb[idx] = f2bf(v);
        else if (sel == 2) vT[(size_t)c * NTOK + row] = f2bf(v);
        else gbuf[idx] = sigm(v);
      }
    }
}

__global__ __launch_bounds__(256) void k_gemm_proj(
    const unsigned short* __restrict__ agh, const unsigned short* __restrict__ agl,
    const unsigned short* __restrict__ wph, const unsigned short* __restrict__ wpl,
    const float* __restrict__ og, float* __restrict__ out) {
  const int nt = blockIdx.x, mt = blockIdx.y;
  f32x4 acc[2][2];
#pragma unroll
  for (int i = 0; i < 2; ++i)
#pragma unroll
    for (int j = 0; j < 2; ++j) acc[i][j] = (f32x4){0.f, 0.f, 0.f, 0.f};
  mfma_core(agh, agl, wph, wpl, ED, mt * 64, nt * 64, acc);
  const int tid = threadIdx.x;
  const int w = tid >> 6, lane = tid & 63;
  const int l15 = lane & 15, kg = lane >> 4;
  const int wr = w >> 1, wc = w & 1;
#pragma unroll
  for (int mi = 0; mi < 2; ++mi)
#pragma unroll
    for (int ni = 0; ni < 2; ++ni) {
      int col = nt * 64 + wc * 32 + ni * 16 + l15;
#pragma unroll
      for (int r = 0; r < 4; ++r) {
        int row = mt * 64 + wr * 32 + mi * 16 + kg * 4 + r;
        size_t idx = (size_t)row * ED + col;
        out[idx] = acc[mi][ni][r] * og[idx];
      }
    }
}

// ---------------- AdaLN combine -> a_mod hi/lo bf16 ----------------
__global__ __launch_bounds__(256) void k_amod(const float* __restrict__ a,
                                              const float* __restrict__ gamma_lin,
                                              const float* __restrict__ beta_lin,
                                              unsigned short* __restrict__ amh,
                                              unsigned short* __restrict__ aml) {
  __shared__ float red[8];
  const int n = blockIdx.x, tid = threadIdx.x;
  const int lane = tid & 63, wid = tid >> 6;
  const float* row = a + (size_t)n * ED;
  float v[3], sum = 0.f, sq = 0.f;
#pragma unroll
  for (int i = 0; i < 3; ++i) { v[i] = row[tid + 256 * i]; sum += v[i]; sq += v[i] * v[i]; }
#pragma unroll
  for (int off = 1; off < 64; off <<= 1) { sum += __shfl_xor(sum, off); sq += __shfl_xor(sq, off); }
  if (lane == 0) { red[wid] = sum; red[4 + wid] = sq; }
  __syncthreads();
  float S = red[0] + red[1] + red[2] + red[3];
  float Q = red[4] + red[5] + red[6] + red[7];
  float mu = S * (1.f / ED);
  float var = Q * (1.f / ED) - mu * mu;
  float rs = rsqrtf(var + 1e-5f);
#pragma unroll
  for (int i = 0; i < 3; ++i) {
    int e = tid + 256 * i;
    float an = (v[i] - mu) * rs;
    size_t idx = (size_t)n * ED + e;
    float val = sigm(gamma_lin[idx]) * an + beta_lin[idx];
    unsigned short h = f2bf(val);
    amh[idx] = h;
    aml[idx] = f2bf(val - bf2f(h));
  }
}

// ---------------- QK^T -> qkl[n][h][m] = q.k^T*scale + beta ----------------
__global__ __launch_bounds__(256) void k_qkw(const unsigned short* __restrict__ qb,
                                             const unsigned short* __restrict__ kb,
                                             const float* __restrict__ beta,
                                             float* __restrict__ qkl) {
  const int mt = blockIdx.x, ntile = blockIdx.y, h = blockIdx.z;
  __shared__ unsigned short qs[64 * 72];
  __shared__ unsigned short ksm[64 * 72];
  const int tid = threadIdx.x;
  const int n0 = ntile * 64, m0 = mt * 64;
  const u16x8 z = {0, 0, 0, 0, 0, 0, 0, 0};
#pragma unroll
  for (int it = 0; it < 2; ++it) {
    int idx = tid + it * 256;
    int row = idx >> 3, c = idx & 7;
    u16x8 vq = z, vk = z;
    if (c < 6) {
      vq = *(const u16x8*)(qb + (size_t)(n0 + row) * ED + h * DH + c * 8);
      vk = *(const u16x8*)(kb + (size_t)(m0 + row) * ED + h * DH + c * 8);
    }
    *(u16x8*)(qs + row * 72 + c * 8) = vq;
    *(u16x8*)(ksm + row * 72 + c * 8) = vk;
  }
  __syncthreads();
  const int wv = tid >> 6, lane = tid & 63;
  const int l15 = lane & 15, kg = lane >> 4;
  f32x4 acc[4];
#pragma unroll
  for (int ct = 0; ct < 4; ++ct) acc[ct] = (f32x4){0.f, 0.f, 0.f, 0.f};
#pragma unroll
  for (int ks2 = 0; ks2 < 2; ++ks2) {
    short8 av = *(const short8*)(qs + (wv * 16 + l15) * 72 + ks2 * 32 + kg * 8);
#pragma unroll
    for (int ct = 0; ct < 4; ++ct) {
      short8 bv = *(const short8*)(ksm + (ct * 16 + l15) * 72 + ks2 * 32 + kg * 8);
      acc[ct] = __builtin_amdgcn_mfma_f32_16x16x32_bf16(av, bv, acc[ct], 0, 0, 0);
    }
  }
  const float scale = 0.14433756729740643f;
#pragma unroll
  for (int ct = 0; ct < 4; ++ct)
#pragma unroll
    for (int r = 0; r < 4; ++r) {
      int nn = n0 + wv * 16 + kg * 4 + r;
      int mm = m0 + ct * 16 + l15;
      qkl[((size_t)nn * NH + h) * NTOK + mm] =
          fmaf(acc[ct][r], scale, beta[(size_t)nn * NTOK + mm]);
    }
}

// ---------------- pair bias (buffered n<NRIDE, inline otherwise) + softmax ----------------
__global__ __launch_bounds__(256, 3) void k_pairsm(const float* __restrict__ pair_rep,
                                                   const float* __restrict__ qkl,
                                                   const float* __restrict__ biasBuf,
                                                   const unsigned short* __restrict__ gw_hi,
                                                   const unsigned short* __restrict__ gw_lo,
                                                   const float* __restrict__ sgw, const float* __restrict__ bw,
                                                   unsigned short* __restrict__ pb) {
  __shared__ float lg[16 * LGS];
  const int n = blockIdx.x;
  const int tid = threadIdx.x;
  const int wv = tid >> 6, lane = tid & 63;
  const int l15 = lane & 15, kg = lane >> 4;
  const bool buffered = (n < NRIDE);

  if (!buffered) {
#define LOADCH(X, CH) do {                                                        \
    const float* xp_ = pair_rep + ((size_t)n * NTOK + (CH) * 16 + l15) * PD + kg * 8; \
    _Pragma("unroll")                                                             \
    for (int q_ = 0; q_ < 4; ++q_) {                                              \
      X[q_ * 2]     = *(const float4*)(xp_ + q_ * 32);                            \
      X[q_ * 2 + 1] = *(const float4*)(xp_ + q_ * 32 + 4);                        \
    }                                                                             \
  } while (0)

    float4 Xa[8], Xb[8];
    LOADCH(Xa, wv);
    LOADCH(Xb, wv + 4);

    short8 bh[4], bl[4];
#pragma unroll
    for (int ks = 0; ks < 4; ++ks)
#pragma unroll
      for (int j = 0; j < 8; ++j) {
        int p = ks * 32 + kg * 8 + j;
        bh[ks][j] = (short)gw_hi[p * 16 + l15];
        bl[ks][j] = (short)gw_lo[p * 16 + l15];
      }
    float sgv[4], bwv[4];
#pragma unroll
    for (int r = 0; r < 4; ++r) { sgv[r] = sgw[kg * 4 + r]; bwv[r] = bw[kg * 4 + r]; }

#define PROC(X, CH) do {                                                          \
    float sum_ = 0.f, sq_ = 0.f;                                                  \
    _Pragma("unroll")                                                             \
    for (int q_ = 0; q_ < 8; ++q_) {                                              \
      sum_ += X[q_].x + X[q_].y + X[q_].z + X[q_].w;                              \
      sq_ = fmaf(X[q_].x, X[q_].x, sq_); sq_ = fmaf(X[q_].y, X[q_].y, sq_);       \
      sq_ = fmaf(X[q_].z, X[q_].z, sq_); sq_ = fmaf(X[q_].w, X[q_].w, sq_);       \
    }                                                                             \
    sum_ += __shfl_xor(sum_, 16); sum_ += __shfl_xor(sum_, 32);                   \
    sq_  += __shfl_xor(sq_, 16);  sq_  += __shfl_xor(sq_, 32);                    \
    float mu_ = sum_ * (1.f / 128.f);                                             \
    float rstd_ = rsqrtf(sq_ * (1.f / 128.f) - mu_ * mu_ + 1e-5f);                \
    f32x4 acc_ = {0.f, 0.f, 0.f, 0.f};                                            \
    _Pragma("unroll")                                                             \
    for (int ks_ = 0; ks_ < 4; ++ks_) {                                           \
      float4 u0_ = X[ks_ * 2], u1_ = X[ks_ * 2 + 1];                              \
      unsigned p0_ = cvtpk(u0_.x, u0_.y), p1_ = cvtpk(u0_.z, u0_.w);              \
      unsigned p2_ = cvtpk(u1_.x, u1_.y), p3_ = cvtpk(u1_.z, u1_.w);              \
      float l0_ = u0_.x - lo2f(p0_), l1_ = u0_.y - hi2f(p0_);                     \
      float l2_ = u0_.z - lo2f(p1_), l3_ = u0_.w - hi2f(p1_);                     \
      float l4_ = u1_.x - lo2f(p2_), l5_ = u1_.y - hi2f(p2_);                     \
      float l6_ = u1_.z - lo2f(p3_), l7_ = u1_.w - hi2f(p3_);                     \
      unsigned q0_ = cvtpk(l0_, l1_), q1_ = cvtpk(l2_, l3_);                      \
      unsigned q2_ = cvtpk(l4_, l5_), q3_ = cvtpk(l6_, l7_);                      \
      u32x4 hp_ = {p0_, p1_, p2_, p3_}, lp_ = {q0_, q1_, q2_, q3_};               \
      short8 ah_ = __builtin_bit_cast(short8, hp_);                               \
      short8 al_ = __builtin_bit_cast(short8, lp_);                               \
      acc_ = __builtin_amdgcn_mfma_f32_16x16x32_bf16(bh[ks_], ah_, acc_, 0, 0, 0);\
      acc_ = __builtin_amdgcn_mfma_f32_16x16x32_bf16(bh[ks_], al_, acc_, 0, 0, 0);\
      acc_ = __builtin_amdgcn_mfma_f32_16x16x32_bf16(bl[ks_], ah_, acc_, 0, 0, 0);\
    }                                                                             \
    _Pragma("unroll")                                                             \
    for (int r_ = 0; r_ < 4; ++r_) {                                              \
      float val_ = rstd_ * (acc_[r_] - mu_ * sgv[r_]) + bwv[r_];                  \
      lg[(kg * 4 + r_) * LGS + (CH) * 16 + l15] = val_;                           \
    }                                                                             \
  } while (0)

    PROC(Xa, wv +  0); LOADCH(Xa, wv +  8);
    PROC(Xb, wv +  4); LOADCH(Xb, wv + 12);
    PROC(Xa, wv +  8); LOADCH(Xa, wv + 16);
    PROC(Xb, wv + 12); LOADCH(Xb, wv + 20);
    PROC(Xa, wv + 16); LOADCH(Xa, wv + 24);
    PROC(Xb, wv + 20); LOADCH(Xb, wv + 28);
    PROC(Xa, wv + 24); LOADCH(Xa, wv + 32);
    PROC(Xb, wv + 28); LOADCH(Xb, wv + 36);
    PROC(Xa, wv + 32); LOADCH(Xa, wv + 40);
    PROC(Xb, wv + 36); LOADCH(Xb, wv + 44);
    PROC(Xa, wv + 40);
    PROC(Xb, wv + 44);
#undef LOADCH
#undef PROC
    __syncthreads();
  }

#pragma unroll
  for (int hh = 0; hh < 4; ++hh) {
    int h = wv * 4 + hh;
    const float* qrow = qkl + ((size_t)n * NH + h) * NTOK;
    const float* brow = biasBuf + ((size_t)n * NH + h) * NTOK;
    float x[12];
    if (buffered) {
#pragma unroll
      for (int i = 0; i < 12; ++i) x[i] = brow[lane + 64 * i] + qrow[lane + 64 * i];
    } else {
#pragma unroll
      for (int i = 0; i < 12; ++i) x[i] = lg[h * LGS + lane + 64 * i] + qrow[lane + 64 * i];
    }
    float mx = x[0];
#pragma unroll
    for (int t = 1; t < 12; ++t) mx = fmaxf(mx, x[t]);
#pragma unroll
    for (int off = 1; off < 64; off <<= 1) mx = fmaxf(mx, __shfl_xor(mx, off));
    float e[12], sm = 0.f;
#pragma unroll
    for (int t = 0; t < 12; ++t) { e[t] = __expf(x[t] - mx); sm += e[t]; }
#pragma unroll
    for (int off = 1; off < 64; off <<= 1) sm += __shfl_xor(sm, off);
    float inv = 1.0f / sm;
    unsigned short* dst = pb + ((size_t)h * NTOK + n) * NTOK;
#pragma unroll
    for (int i = 0; i < 12; ++i) dst[lane + 64 * i] = f2bf(e[i] * inv);
  }
}

// ---------------- PV: attn*gate -> ag hi/lo bf16 (double-buffered) ----------------
__global__ __launch_bounds__(256) void k_pv(const unsigned short* __restrict__ wb,
                                            const unsigned short* __restrict__ vT,
                                            const float* __restrict__ gbuf,
                                            unsigned short* __restrict__ agh,
                                            unsigned short* __restrict__ agl) {
  const int ntile = blockIdx.x, h = blockIdx.y;
  const int n0 = ntile * 64;
  __shared__ unsigned short wsm[2][64 * 40];
  __shared__ unsigned short vtm[2][48 * 40];
  const int tid = threadIdx.x;
  const int wv = tid >> 6, lane = tid & 63, l15 = lane & 15, kg = lane >> 4;
  const int srow = tid >> 2, sc = tid & 3;
  const unsigned short* wsrc = wb + ((size_t)h * NTOK + (n0 + srow)) * NTOK + sc * 8;
  const unsigned short* vsrc = (tid < 192)
      ? vT + (size_t)(h * DH + srow) * NTOK + sc * 8 : nullptr;
  f32x4 acc[3];
#pragma unroll
  for (int dt = 0; dt < 3; ++dt) acc[dt] = (f32x4){0.f, 0.f, 0.f, 0.f};

  *(u16x8*)(wsm[0] + srow * 40 + sc * 8) = *(const u16x8*)(wsrc);
  if (tid < 192)
    *(u16x8*)(vtm[0] + srow * 40 + sc * 8) = *(const u16x8*)(vsrc);
  __syncthreads();

  int buf = 0;
  for (int k0 = 0; k0 < NTOK; k0 += 32) {
    if (k0 + 32 < NTOK) {
      *(u16x8*)(wsm[buf ^ 1] + srow * 40 + sc * 8) = *(const u16x8*)(wsrc + k0 + 32);
      if (tid < 192)
        *(u16x8*)(vtm[buf ^ 1] + srow * 40 + sc * 8) = *(const u16x8*)(vsrc + k0 + 32);
    }
    short8 av = *(const short8*)(wsm[buf] + (wv * 16 + l15) * 40 + kg * 8);
#pragma unroll
    for (int dt = 0; dt < 3; ++dt) {
      short8 bv = *(const short8*)(vtm[buf] + (dt * 16 + l15) * 40 + kg * 8);
      acc[dt] = __builtin_amdgcn_mfma_f32_16x16x32_bf16(av, bv, acc[dt], 0, 0, 0);
    }
    __syncthreads();
    buf ^= 1;
  }
#pragma unroll
  for (int dt = 0; dt < 3; ++dt)
#pragma unroll
    for (int r = 0; r < 4; ++r) {
      int nn = n0 + wv * 16 + kg * 4 + r;
      int col = h * DH + dt * 16 + l15;
      size_t idx = (size_t)nn * ED + col;
      float val = acc[dt][r] * gbuf[idx];
      unsigned short hb = f2bf(val);
      agh[idx] = hb;
      agl[idx] = f2bf(val - bf2f(hb));
    }
}

extern "C" void kernel_launch(void* const* d_in, const int* in_sizes, int n_in,
                              void* d_out, int out_size, void* d_ws, size_t ws_size,
                              hipStream_t stream) {
  const float* a    = (const float*)d_in[0];
  const float* s    = (const float*)d_in[1];
  const float* pair = (const float*)d_in[2];
  const float* beta = (const float*)d_in[3];
  const float* wag  = (const float*)d_in[4];
  const float* wab  = (const float*)d_in[5];
  const float* wq   = (const float*)d_in[6];
  const float* bq   = (const float*)d_in[7];
  const float* wk   = (const float*)d_in[8];
  const float* wvp  = (const float*)d_in[9];
  const float* lng  = (const float*)d_in[10];
  const float* lnb  = (const float*)d_in[11];
  const float* wpair= (const float*)d_in[12];
  const float* wg   = (const float*)d_in[13];
  const float* wproj= (const float*)d_in[14];
  const float* wo   = (const float*)d_in[15];
  const float* bo   = (const float*)d_in[16];
  float* out = (float*)d_out;

  if (ws_size < WS_NEED) return;

  char* ws = (char*)d_ws;
  unsigned short* snh  = (unsigned short*)(ws + OFF_SNH);
  unsigned short* snl  = (unsigned short*)(ws + OFF_SNL);
  unsigned short* srh  = (unsigned short*)(ws + OFF_SRH);
  unsigned short* srl  = (unsigned short*)(ws + OFF_SRL);
  float*          gaml = (float*)(ws + OFF_GAM);
  float*          betl = (float*)(ws + OFF_BET);
  float*          og   = (float*)(ws + OFF_OG);
  unsigned short* amh  = (unsigned short*)(ws + OFF_AMH);
  unsigned short* aml  = (unsigned short*)(ws + OFF_AML);
  unsigned short* qb   = (unsigned short*)(ws + OFF_QB);
  unsigned short* kb   = (unsigned short*)(ws + OFF_KB);
  unsigned short* vT   = (unsigned short*)(ws + OFF_VT);
  float*          gbuf = (float*)(ws + OFF_GBUF);
  unsigned short* agh  = (unsigned short*)(ws + OFF_AGH);
  unsigned short* agl  = (unsigned short*)(ws + OFF_AGL);
  unsigned short* wsmh = (unsigned short*)(ws + OFF_WSMH);
  unsigned short* wsml = (unsigned short*)(ws + OFF_WSML);
  unsigned short* wqh  = (unsigned short*)(ws + OFF_WQH);
  unsigned short* wql  = (unsigned short*)(ws + OFF_WQL);
  unsigned short* wph  = (unsigned short*)(ws + OFF_WPH);
  unsigned short* wpl  = (unsigned short*)(ws + OFF_WPL);
  unsigned short* gwh  = (unsigned short*)(ws + OFF_GWH);
  unsigned short* gwl  = (unsigned short*)(ws + OFF_GWL);
  float*          sgw  = (float*)(ws + OFF_SGW);
  float*          bw   = sgw + 16;
  float*          qkl  = (float*)(ws + OFF_QKL);
  unsigned short* pb   = (unsigned short*)(ws + OFF_PB);
  float*          bb   = (float*)(ws + OFF_BB);

  hipLaunchKernelGGL(k_wcvt, dim3(24, 24, 9), dim3(256), 0, stream,
                     wag, wab, wo, wq, wk, wvp, wg, wproj, lng, lnb, wpair, s,
                     wsmh, wsml, wqh, wql, wph, wpl, gwh, gwl, sgw, bw,
                     snh, snl, srh, srl);
  hipLaunchKernelGGL(k_gemm_small, dim3(36, 12), dim3(256), 0, stream,
                     snh, snl, srh, srl, wsmh, wsml, bo, gaml, betl, og);
  hipLaunchKernelGGL(k_amod, dim3(768), dim3(256), 0, stream, a, gaml, betl, amh, aml);
  hipLaunchKernelGGL(k_gemm_qkvg, dim3(48, 16), dim3(256), 0, stream,
                     amh, aml, wqh, wql, bq, pair, gwh, gwl, sgw, bw, bb,
                     qb, kb, vT, gbuf);
  hipLaunchKernelGGL(k_qkw, dim3(12, 12, 16), dim3(256), 0, stream, qb, kb, beta, qkl);
  hipLaunchKernelGGL(k_pairsm, dim3(768), dim3(256), 0, stream,
                     pair, qkl, bb, gwh, gwl, sgw, bw, pb);
  hipLaunchKernelGGL(k_pv, dim3(12, 16), dim3(256), 0, stream, pb, vT, gbuf, agh, agl);
  hipLaunchKernelGGL(k_gemm_proj, dim3(12, 12), dim3(256), 0, stream,
                     agh, agl, wph, wpl, og, out);
}

// Round 17
// 180.149 us; speedup vs baseline: 1.0428x; 1.0428x over previous
//
#include <hip/hip_runtime.h>
#include <hip/hip_bf16.h>

typedef __attribute__((ext_vector_type(8))) short short8;
typedef __attribute__((ext_vector_type(8))) unsigned short u16x8;
typedef __attribute__((ext_vector_type(4))) unsigned short u16x4;
typedef __attribute__((ext_vector_type(4))) float f32x4;
typedef __attribute__((ext_vector_type(4))) unsigned u32x4;

#define NTOK 768
#define ED   768
#define SD   384
#define PD   128
#define NH   16
#define DH   48
#define LGS  778
#define NRIDE 192   // pair rows computed by k_gemm_qkvg rider blocks (dispatched first)

__device__ __forceinline__ unsigned short f2bf(float x) {
  unsigned u = __builtin_bit_cast(unsigned, x);
  u += 0x7FFFu + ((u >> 16) & 1u);
  return (unsigned short)(u >> 16);
}
__device__ __forceinline__ float bf2f(unsigned short b) {
  unsigned u = ((unsigned)b) << 16;
  return __builtin_bit_cast(float, u);
}
__device__ __forceinline__ float sigm(float x) { return 1.0f / (1.0f + __expf(-x)); }

__device__ __forceinline__ unsigned cvtpk(float a, float b) {
  unsigned r;
  asm("v_cvt_pk_bf16_f32 %0, %1, %2" : "=v"(r) : "v"(a), "v"(b));
  return r;
}
__device__ __forceinline__ float lo2f(unsigned p) {
  return __builtin_bit_cast(float, p << 16);
}
__device__ __forceinline__ float hi2f(unsigned p) {
  return __builtin_bit_cast(float, p & 0xFFFF0000u);
}

__device__ __forceinline__ void gl2lds(const unsigned short* g, unsigned short* l) {
  __builtin_amdgcn_global_load_lds(
      (const __attribute__((address_space(1))) unsigned int*)g,
      (__attribute__((address_space(3))) unsigned int*)l, 16, 0, 0);
}

// ---------------- workspace layout (bytes) ----------------
constexpr size_t SZ_SN   = (size_t)NTOK * SD * 2;
constexpr size_t OFF_SNH = 0;
constexpr size_t OFF_SNL = OFF_SNH + SZ_SN;
constexpr size_t OFF_SRH = OFF_SNL + SZ_SN;
constexpr size_t OFF_SRL = OFF_SRH + SZ_SN;
constexpr size_t OFF_GAM = OFF_SRL + SZ_SN;                // f32 [768][768]
constexpr size_t OFF_BET = OFF_GAM + 2359296;
constexpr size_t OFF_OG  = OFF_BET + 2359296;
constexpr size_t OFF_AMH = OFF_OG  + 2359296;              // bf16 [768][768]
constexpr size_t OFF_AML = OFF_AMH + 1179648;
constexpr size_t OFF_QB  = OFF_AML + 1179648;
constexpr size_t OFF_KB  = OFF_QB  + 1179648;
constexpr size_t OFF_VT  = OFF_KB  + 1179648;              // bf16 [768 hd][768 m]
constexpr size_t OFF_GBUF= OFF_VT  + 1179648;              // f32
constexpr size_t OFF_AGH = OFF_GBUF+ 2359296;
constexpr size_t OFF_AGL = OFF_AGH + 1179648;
constexpr size_t OFF_WSMH= OFF_AGL + 1179648;              // [2304][384] bf16
constexpr size_t OFF_WSML= OFF_WSMH+ 1769472;
constexpr size_t OFF_WQH = OFF_WSML+ 1769472;              // [3072][768] bf16
constexpr size_t OFF_WQL = OFF_WQH + 4718592;
constexpr size_t OFF_WPH = OFF_WQL + 4718592;              // [768][768] bf16
constexpr size_t OFF_WPL = OFF_WPH + 1179648;
constexpr size_t OFF_GWH = OFF_WPL + 1179648;
constexpr size_t OFF_GWL = OFF_GWH + 4096;
constexpr size_t OFF_SGW = OFF_GWL + 4096;
constexpr size_t OFF_QKL = OFF_SGW + 4096;                 // f32 [768 n][16 h][768 m]
constexpr size_t OFF_PB  = OFF_QKL + 37748736;             // bf16 [16 h][768 n][768 m]
constexpr size_t OFF_BB  = OFF_PB  + 18874368;             // f32 [192 n][16 h][768 m]
constexpr size_t WS_NEED = OFF_BB  + 9437184;

// ---------------- preprocessing: weights + setup + LN(s) ----------------
__global__ __launch_bounds__(256) void k_wcvt(
    const float* __restrict__ wag, const float* __restrict__ wab, const float* __restrict__ wo,
    const float* __restrict__ wq, const float* __restrict__ wk, const float* __restrict__ wv,
    const float* __restrict__ wg, const float* __restrict__ wp,
    const float* __restrict__ lng, const float* __restrict__ lnb,
    const float* __restrict__ wpair, const float* __restrict__ s,
    unsigned short* __restrict__ wsmh, unsigned short* __restrict__ wsml,
    unsigned short* __restrict__ wqh, unsigned short* __restrict__ wql,
    unsigned short* __restrict__ wph, unsigned short* __restrict__ wpl,
    unsigned short* __restrict__ gwh, unsigned short* __restrict__ gwl,
    float* __restrict__ sgw, float* __restrict__ bw,
    unsigned short* __restrict__ snh, unsigned short* __restrict__ snl,
    unsigned short* __restrict__ srh, unsigned short* __restrict__ srl) {
  const int tid = threadIdx.x;
  if (blockIdx.z == 8) {
    const int gid = blockIdx.y * 24 + blockIdx.x;
    if (gid == 192) {
      if (tid < 128) {
        float g = lng[tid];
        for (int hh = 0; hh < 16; ++hh) {
          float gwv = g * wpair[tid * 16 + hh];
          unsigned short hb = f2bf(gwv);
          gwh[tid * 16 + hh] = hb;
          gwl[tid * 16 + hh] = f2bf(gwv - bf2f(hb));
        }
      }
      if (tid < 16) {
        float sv = 0.f, bb = 0.f;
        for (int p = 0; p < 128; ++p) {
          float w = wpair[p * 16 + tid];
          sv += lng[p] * w;
          bb += lnb[p] * w;
        }
        sgw[tid] = sv;
        bw[tid]  = bb;
      }
      return;
    }
    if (gid > 192) return;
    const int n = gid * 4 + (tid >> 6);
    const int lane = tid & 63;
    const float* row = s + (size_t)n * SD;
    float v[6], sum = 0.f, sq = 0.f;
#pragma unroll
    for (int i = 0; i < 6; ++i) { v[i] = row[lane + 64 * i]; sum += v[i]; sq += v[i] * v[i]; }
#pragma unroll
    for (int off = 1; off < 64; off <<= 1) { sum += __shfl_xor(sum, off); sq += __shfl_xor(sq, off); }
    float mu = sum * (1.f / SD);
    float var = sq * (1.f / SD) - mu * mu;
    float rs = rsqrtf(var + 1e-5f);
#pragma unroll
    for (int i = 0; i < 6; ++i) {
      size_t idx = (size_t)n * SD + lane + 64 * i;
      float x = v[i];
      unsigned short xh = f2bf(x);
      srh[idx] = xh; srl[idx] = f2bf(x - bf2f(xh));
      float y = (x - mu) * rs;
      unsigned short yh = f2bf(y);
      snh[idx] = yh; snl[idx] = f2bf(y - bf2f(yh));
    }
    return;
  }
  const int id = blockIdx.z;
  const float* src; int Ksrc; unsigned short *dh, *dl; int n0; int Kd;
  switch (id) {
    case 0: src = wag; Ksrc = 384; dh = wsmh; dl = wsml; n0 = 0;    Kd = 384; break;
    case 1: src = wab; Ksrc = 384; dh = wsmh; dl = wsml; n0 = 768;  Kd = 384; break;
    case 2: src = wo;  Ksrc = 384; dh = wsmh; dl = wsml; n0 = 1536; Kd = 384; break;
    case 3: src = wq;  Ksrc = 768; dh = wqh;  dl = wql;  n0 = 0;    Kd = 768; break;
    case 4: src = wk;  Ksrc = 768; dh = wqh;  dl = wql;  n0 = 768;  Kd = 768; break;
    case 5: src = wv;  Ksrc = 768; dh = wqh;  dl = wql;  n0 = 1536; Kd = 768; break;
    case 6: src = wg;  Ksrc = 768; dh = wqh;  dl = wql;  n0 = 2304; Kd = 768; break;
    default: src = wp; Ksrc = 768; dh = wph;  dl = wpl;  n0 = 0;    Kd = 768; break;
  }
  const int kt = blockIdx.x, ntile = blockIdx.y;
  if (kt * 32 >= Ksrc) return;
  __shared__ float t[32][33];
  const int r = tid >> 3, c4 = (tid & 7) * 4;
  float4 v = *(const float4*)(src + (size_t)(kt * 32 + r) * 768 + ntile * 32 + c4);
  t[r][c4 + 0] = v.x; t[r][c4 + 1] = v.y; t[r][c4 + 2] = v.z; t[r][c4 + 3] = v.w;
  __syncthreads();
  u16x4 hv, lv;
#pragma unroll
  for (int j = 0; j < 4; ++j) {
    float x = t[c4 + j][r];
    unsigned short hb = f2bf(x);
    hv[j] = hb;
    lv[j] = f2bf(x - bf2f(hb));
  }
  size_t drow = (size_t)(n0 + ntile * 32 + r) * Kd + kt * 32 + c4;
  *(u16x4*)(dh + drow) = hv;
  *(u16x4*)(dl + drow) = lv;
}

// ---------------- rider: pair bias for one n-row, registers -> global bb ----------------
__device__ __forceinline__ void pair_bias_rows_to_global(
    int n, const float* __restrict__ pair_rep,
    const unsigned short* __restrict__ gw_hi, const unsigned short* __restrict__ gw_lo,
    const float* __restrict__ sgw, const float* __restrict__ bw,
    float* __restrict__ bb) {
  const int tid = threadIdx.x;
  const int wv = tid >> 6, lane = tid & 63;
  const int l15 = lane & 15, kg = lane >> 4;

#define LOADCH2(X, CH) do {                                                       \
    const float* xp_ = pair_rep + ((size_t)n * NTOK + (CH) * 16 + l15) * PD + kg * 8; \
    _Pragma("unroll")                                                             \
    for (int q_ = 0; q_ < 4; ++q_) {                                              \
      X[q_ * 2]     = *(const float4*)(xp_ + q_ * 32);                            \
      X[q_ * 2 + 1] = *(const float4*)(xp_ + q_ * 32 + 4);                        \
    }                                                                             \
  } while (0)

  float4 Xa[8], Xb[8];
  LOADCH2(Xa, wv);
  LOADCH2(Xb, wv + 4);

  short8 bh[4], bl[4];
#pragma unroll
  for (int ks = 0; ks < 4; ++ks)
#pragma unroll
    for (int j = 0; j < 8; ++j) {
      int p = ks * 32 + kg * 8 + j;
      bh[ks][j] = (short)gw_hi[p * 16 + l15];
      bl[ks][j] = (short)gw_lo[p * 16 + l15];
    }
  float sgv[4], bwv[4];
#pragma unroll
  for (int r = 0; r < 4; ++r) { sgv[r] = sgw[kg * 4 + r]; bwv[r] = bw[kg * 4 + r]; }

#define PROC2(X, CH) do {                                                         \
    float sum_ = 0.f, sq_ = 0.f;                                                  \
    _Pragma("unroll")                                                             \
    for (int q_ = 0; q_ < 8; ++q_) {                                              \
      sum_ += X[q_].x + X[q_].y + X[q_].z + X[q_].w;                              \
      sq_ = fmaf(X[q_].x, X[q_].x, sq_); sq_ = fmaf(X[q_].y, X[q_].y, sq_);       \
      sq_ = fmaf(X[q_].z, X[q_].z, sq_); sq_ = fmaf(X[q_].w, X[q_].w, sq_);       \
    }                                                                             \
    sum_ += __shfl_xor(sum_, 16); sum_ += __shfl_xor(sum_, 32);                   \
    sq_  += __shfl_xor(sq_, 16);  sq_  += __shfl_xor(sq_, 32);                    \
    float mu_ = sum_ * (1.f / 128.f);                                             \
    float rstd_ = rsqrtf(sq_ * (1.f / 128.f) - mu_ * mu_ + 1e-5f);                \
    f32x4 acc_ = {0.f, 0.f, 0.f, 0.f};                                            \
    _Pragma("unroll")                                                             \
    for (int ks_ = 0; ks_ < 4; ++ks_) {                                           \
      float4 u0_ = X[ks_ * 2], u1_ = X[ks_ * 2 + 1];                              \
      unsigned p0_ = cvtpk(u0_.x, u0_.y), p1_ = cvtpk(u0_.z, u0_.w);              \
      unsigned p2_ = cvtpk(u1_.x, u1_.y), p3_ = cvtpk(u1_.z, u1_.w);              \
      float l0_ = u0_.x - lo2f(p0_), l1_ = u0_.y - hi2f(p0_);                     \
      float l2_ = u0_.z - lo2f(p1_), l3_ = u0_.w - hi2f(p1_);                     \
      float l4_ = u1_.x - lo2f(p2_), l5_ = u1_.y - hi2f(p2_);                     \
      float l6_ = u1_.z - lo2f(p3_), l7_ = u1_.w - hi2f(p3_);                     \
      unsigned q0_ = cvtpk(l0_, l1_), q1_ = cvtpk(l2_, l3_);                      \
      unsigned q2_ = cvtpk(l4_, l5_), q3_ = cvtpk(l6_, l7_);                      \
      u32x4 hp_ = {p0_, p1_, p2_, p3_}, lp_ = {q0_, q1_, q2_, q3_};               \
      short8 ah_ = __builtin_bit_cast(short8, hp_);                               \
      short8 al_ = __builtin_bit_cast(short8, lp_);                               \
      acc_ = __builtin_amdgcn_mfma_f32_16x16x32_bf16(bh[ks_], ah_, acc_, 0, 0, 0);\
      acc_ = __builtin_amdgcn_mfma_f32_16x16x32_bf16(bh[ks_], al_, acc_, 0, 0, 0);\
      acc_ = __builtin_amdgcn_mfma_f32_16x16x32_bf16(bl[ks_], ah_, acc_, 0, 0, 0);\
    }                                                                             \
    _Pragma("unroll")                                                             \
    for (int r_ = 0; r_ < 4; ++r_) {                                              \
      float val_ = rstd_ * (acc_[r_] - mu_ * sgv[r_]) + bwv[r_];                  \
      bb[(size_t)n * (NH * NTOK) + (kg * 4 + r_) * NTOK + (CH) * 16 + l15] = val_;\
    }                                                                             \
  } while (0)

  PROC2(Xa, wv +  0); LOADCH2(Xa, wv +  8);
  PROC2(Xb, wv +  4); LOADCH2(Xb, wv + 12);
  PROC2(Xa, wv +  8); LOADCH2(Xa, wv + 16);
  PROC2(Xb, wv + 12); LOADCH2(Xb, wv + 20);
  PROC2(Xa, wv + 16); LOADCH2(Xa, wv + 24);
  PROC2(Xb, wv + 20); LOADCH2(Xb, wv + 28);
  PROC2(Xa, wv + 24); LOADCH2(Xa, wv + 32);
  PROC2(Xb, wv + 28); LOADCH2(Xb, wv + 36);
  PROC2(Xa, wv + 32); LOADCH2(Xa, wv + 40);
  PROC2(Xb, wv + 36); LOADCH2(Xb, wv + 44);
  PROC2(Xa, wv + 40);
  PROC2(Xb, wv + 44);
#undef LOADCH2
#undef PROC2
}

// ---------------- split-bf16 MFMA GEMM core: 64x64 tile, 256 threads ----------------
__device__ __forceinline__ void mfma_core(
    const unsigned short* __restrict__ Ah, const unsigned short* __restrict__ Al,
    const unsigned short* __restrict__ Bh, const unsigned short* __restrict__ Bl,
    int K, int mBase, int nBase, f32x4 acc[2][2]) {
  __shared__ unsigned short lds[2][4][4096];
  const int tid = threadIdx.x;
  const int w = tid >> 6, lane = tid & 63;
  const int l15 = lane & 15, kg = lane >> 4;
  const int wr = w >> 1, wc = w & 1;

  size_t offA[2], offB[2];
  int ldsw[2];
#pragma unroll
  for (int i = 0; i < 2; ++i) {
    int chunk = w * 128 + i * 64 + lane;
    int row = chunk >> 3;
    int slot = (chunk & 7) ^ (row & 7);
    offA[i] = (size_t)(mBase + row) * K + slot * 8;
    offB[i] = (size_t)(nBase + row) * K + slot * 8;
    ldsw[i] = w * 1024 + i * 512;
  }
  auto stage = [&](int b, int k0) {
#pragma unroll
    for (int i = 0; i < 2; ++i) {
      gl2lds(Ah + offA[i] + k0, &lds[b][0][ldsw[i]]);
      gl2lds(Al + offA[i] + k0, &lds[b][1][ldsw[i]]);
      gl2lds(Bh + offB[i] + k0, &lds[b][2][ldsw[i]]);
      gl2lds(Bl + offB[i] + k0, &lds[b][3][ldsw[i]]);
    }
  };

  stage(0, 0);
  int buf = 0;
  for (int k0 = 64; k0 <= K; k0 += 64) {
    __syncthreads();
    if (k0 < K) stage(buf ^ 1, k0);
#pragma unroll
    for (int kk = 0; kk < 2; ++kk) {
      short8 ah[2], al[2], bh4[2], bl4[2];
#pragma unroll
      for (int mi = 0; mi < 2; ++mi) {
        int row = wr * 32 + mi * 16 + l15;
        int kb = kk * 64 + kg * 16;
        int idx = row * 64 + ((kb ^ ((row & 7) << 4)) >> 1);
        ah[mi] = *(const short8*)&lds[buf][0][idx];
        al[mi] = *(const short8*)&lds[buf][1][idx];
      }
#pragma unroll
      for (int ni = 0; ni < 2; ++ni) {
        int row = wc * 32 + ni * 16 + l15;
        int kb = kk * 64 + kg * 16;
        int idx = row * 64 + ((kb ^ ((row & 7) << 4)) >> 1);
        bh4[ni] = *(const short8*)&lds[buf][2][idx];
        bl4[ni] = *(const short8*)&lds[buf][3][idx];
      }
#pragma unroll
      for (int mi = 0; mi < 2; ++mi)
#pragma unroll
        for (int ni = 0; ni < 2; ++ni) {
          acc[mi][ni] = __builtin_amdgcn_mfma_f32_16x16x32_bf16(ah[mi], bh4[ni], acc[mi][ni], 0, 0, 0);
          acc[mi][ni] = __builtin_amdgcn_mfma_f32_16x16x32_bf16(al[mi], bh4[ni], acc[mi][ni], 0, 0, 0);
          acc[mi][ni] = __builtin_amdgcn_mfma_f32_16x16x32_bf16(ah[mi], bl4[ni], acc[mi][ni], 0, 0, 0);
        }
    }
    buf ^= 1;
  }
}

// ---------------- GEMM instances (64x64 tiles, 256-thread blocks) ----------------
__global__ __launch_bounds__(256) void k_gemm_small(
    const unsigned short* __restrict__ snh, const unsigned short* __restrict__ snl,
    const unsigned short* __restrict__ srh, const unsigned short* __restrict__ srl,
    const unsigned short* __restrict__ wsmh, const unsigned short* __restrict__ wsml,
    const float* __restrict__ bo,
    float* __restrict__ gaml, float* __restrict__ betl, float* __restrict__ og) {
  const int nt = blockIdx.x, mt = blockIdx.y;
  const unsigned short* Ah = (nt < 24) ? snh : srh;
  const unsigned short* Al = (nt < 24) ? snl : srl;
  f32x4 acc[2][2];
#pragma unroll
  for (int i = 0; i < 2; ++i)
#pragma unroll
    for (int j = 0; j < 2; ++j) acc[i][j] = (f32x4){0.f, 0.f, 0.f, 0.f};
  mfma_core(Ah, Al, wsmh, wsml, SD, mt * 64, nt * 64, acc);
  const int tid = threadIdx.x;
  const int w = tid >> 6, lane = tid & 63;
  const int l15 = lane & 15, kg = lane >> 4;
  const int wr = w >> 1, wc = w & 1;
#pragma unroll
  for (int mi = 0; mi < 2; ++mi)
#pragma unroll
    for (int ni = 0; ni < 2; ++ni) {
      int col = nt * 64 + wc * 32 + ni * 16 + l15;
#pragma unroll
      for (int r = 0; r < 4; ++r) {
        int row = mt * 64 + wr * 32 + mi * 16 + kg * 4 + r;
        float v = acc[mi][ni][r];
        if (col < 768) gaml[(size_t)row * ED + col] = v;
        else if (col < 1536) betl[(size_t)row * ED + col - 768] = v;
        else og[(size_t)row * ED + col - 1536] = sigm(v + bo[col - 1536]);
      }
    }
}

// qkvg GEMM + register-direct pair riders (riders at LOW mt -> dispatched FIRST)
__global__ __launch_bounds__(256) void k_gemm_qkvg(
    const unsigned short* __restrict__ amh, const unsigned short* __restrict__ aml,
    const unsigned short* __restrict__ wqh, const unsigned short* __restrict__ wql,
    const float* __restrict__ bq,
    const float* __restrict__ pair_rep,
    const unsigned short* __restrict__ gwh, const unsigned short* __restrict__ gwl,
    const float* __restrict__ sgw, const float* __restrict__ bw,
    float* __restrict__ biasBuf,
    unsigned short* __restrict__ qb, unsigned short* __restrict__ kb,
    unsigned short* __restrict__ vT, float* __restrict__ gbuf) {
  const int nt = blockIdx.x, mtR = blockIdx.y;
  if (mtR < 4) {                        // rider: rows 0..191, dispatched first
    pair_bias_rows_to_global(mtR * 48 + nt, pair_rep, gwh, gwl, sgw, bw, biasBuf);
    return;
  }
  const int mt = mtR - 4;
  f32x4 acc[2][2];
#pragma unroll
  for (int i = 0; i < 2; ++i)
#pragma unroll
    for (int j = 0; j < 2; ++j) acc[i][j] = (f32x4){0.f, 0.f, 0.f, 0.f};
  mfma_core(amh, aml, wqh, wql, ED, mt * 64, nt * 64, acc);
  const int tid = threadIdx.x;
  const int w = tid >> 6, lane = tid & 63;
  const int l15 = lane & 15, kg = lane >> 4;
  const int wr = w >> 1, wc = w & 1;
  const int sel = nt / 12;
#pragma unroll
  for (int mi = 0; mi < 2; ++mi)
#pragma unroll
    for (int ni = 0; ni < 2; ++ni) {
      int col = nt * 64 + wc * 32 + ni * 16 + l15;
      int c = col - sel * 768;
#pragma unroll
      for (int r = 0; r < 4; ++r) {
        int row = mt * 64 + wr * 32 + mi * 16 + kg * 4 + r;
        float v = acc[mi][ni][r];
        size_t idx = (size_t)row * ED + c;
        if (sel == 0) qb[idx] = f2bf(v + bq[c]);
        else if (sel == 1) kb[idx] = f2bf(v);
        else if (sel == 2) vT[(size_t)c * NTOK + row] = f2bf(v);
        else gbuf[idx] = sigm(v);
      }
    }
}

__global__ __launch_bounds__(256) void k_gemm_proj(
    const unsigned short* __restrict__ agh, const unsigned short* __restrict__ agl,
    const unsigned short* __restrict__ wph, const unsigned short* __restrict__ wpl,
    const float* __restrict__ og, float* __restrict__ out) {
  const int nt = blockIdx.x, mt = blockIdx.y;
  f32x4 acc[2][2];
#pragma unroll
  for (int i = 0; i < 2; ++i)
#pragma unroll
    for (int j = 0; j < 2; ++j) acc[i][j] = (f32x4){0.f, 0.f, 0.f, 0.f};
  mfma_core(agh, agl, wph, wpl, ED, mt * 64, nt * 64, acc);
  const int tid = threadIdx.x;
  const int w = tid >> 6, lane = tid & 63;
  const int l15 = lane & 15, kg = lane >> 4;
  const int wr = w >> 1, wc = w & 1;
#pragma unroll
  for (int mi = 0; mi < 2; ++mi)
#pragma unroll
    for (int ni = 0; ni < 2; ++ni) {
      int col = nt * 64 + wc * 32 + ni * 16 + l15;
#pragma unroll
      for (int r = 0; r < 4; ++r) {
        int row = mt * 64 + wr * 32 + mi * 16 + kg * 4 + r;
        size_t idx = (size_t)row * ED + col;
        out[idx] = acc[mi][ni][r] * og[idx];
      }
    }
}

// ---------------- AdaLN combine -> a_mod hi/lo bf16 ----------------
__global__ __launch_bounds__(256) void k_amod(const float* __restrict__ a,
                                              const float* __restrict__ gamma_lin,
                                              const float* __restrict__ beta_lin,
                                              unsigned short* __restrict__ amh,
                                              unsigned short* __restrict__ aml) {
  __shared__ float red[8];
  const int n = blockIdx.x, tid = threadIdx.x;
  const int lane = tid & 63, wid = tid >> 6;
  const float* row = a + (size_t)n * ED;
  float v[3], sum = 0.f, sq = 0.f;
#pragma unroll
  for (int i = 0; i < 3; ++i) { v[i] = row[tid + 256 * i]; sum += v[i]; sq += v[i] * v[i]; }
#pragma unroll
  for (int off = 1; off < 64; off <<= 1) { sum += __shfl_xor(sum, off); sq += __shfl_xor(sq, off); }
  if (lane == 0) { red[wid] = sum; red[4 + wid] = sq; }
  __syncthreads();
  float S = red[0] + red[1] + red[2] + red[3];
  float Q = red[4] + red[5] + red[6] + red[7];
  float mu = S * (1.f / ED);
  float var = Q * (1.f / ED) - mu * mu;
  float rs = rsqrtf(var + 1e-5f);
#pragma unroll
  for (int i = 0; i < 3; ++i) {
    int e = tid + 256 * i;
    float an = (v[i] - mu) * rs;
    size_t idx = (size_t)n * ED + e;
    float val = sigm(gamma_lin[idx]) * an + beta_lin[idx];
    unsigned short h = f2bf(val);
    amh[idx] = h;
    aml[idx] = f2bf(val - bf2f(h));
  }
}

// ---------------- QK^T -> qkl[n][h][m] = q.k^T*scale + beta ----------------
__global__ __launch_bounds__(256) void k_qkw(const unsigned short* __restrict__ qb,
                                             const unsigned short* __restrict__ kb,
                                             const float* __restrict__ beta,
                                             float* __restrict__ qkl) {
  const int mt = blockIdx.x, ntile = blockIdx.y, h = blockIdx.z;
  __shared__ unsigned short qs[64 * 72];
  __shared__ unsigned short ksm[64 * 72];
  const int tid = threadIdx.x;
  const int n0 = ntile * 64, m0 = mt * 64;
  const u16x8 z = {0, 0, 0, 0, 0, 0, 0, 0};
#pragma unroll
  for (int it = 0; it < 2; ++it) {
    int idx = tid + it * 256;
    int row = idx >> 3, c = idx & 7;
    u16x8 vq = z, vk = z;
    if (c < 6) {
      vq = *(const u16x8*)(qb + (size_t)(n0 + row) * ED + h * DH + c * 8);
      vk = *(const u16x8*)(kb + (size_t)(m0 + row) * ED + h * DH + c * 8);
    }
    *(u16x8*)(qs + row * 72 + c * 8) = vq;
    *(u16x8*)(ksm + row * 72 + c * 8) = vk;
  }
  __syncthreads();
  const int wv = tid >> 6, lane = tid & 63;
  const int l15 = lane & 15, kg = lane >> 4;
  f32x4 acc[4];
#pragma unroll
  for (int ct = 0; ct < 4; ++ct) acc[ct] = (f32x4){0.f, 0.f, 0.f, 0.f};
#pragma unroll
  for (int ks2 = 0; ks2 < 2; ++ks2) {
    short8 av = *(const short8*)(qs + (wv * 16 + l15) * 72 + ks2 * 32 + kg * 8);
#pragma unroll
    for (int ct = 0; ct < 4; ++ct) {
      short8 bv = *(const short8*)(ksm + (ct * 16 + l15) * 72 + ks2 * 32 + kg * 8);
      acc[ct] = __builtin_amdgcn_mfma_f32_16x16x32_bf16(av, bv, acc[ct], 0, 0, 0);
    }
  }
  const float scale = 0.14433756729740643f;
#pragma unroll
  for (int ct = 0; ct < 4; ++ct)
#pragma unroll
    for (int r = 0; r < 4; ++r) {
      int nn = n0 + wv * 16 + kg * 4 + r;
      int mm = m0 + ct * 16 + l15;
      qkl[((size_t)nn * NH + h) * NTOK + mm] =
          fmaf(acc[ct][r], scale, beta[(size_t)nn * NTOK + mm]);
    }
}

// ---------------- pair bias (buffered n<NRIDE, inline otherwise) + softmax ----------------
__global__ __launch_bounds__(256, 3) void k_pairsm(const float* __restrict__ pair_rep,
                                                   const float* __restrict__ qkl,
                                                   const float* __restrict__ biasBuf,
                                                   const unsigned short* __restrict__ gw_hi,
                                                   const unsigned short* __restrict__ gw_lo,
                                                   const float* __restrict__ sgw, const float* __restrict__ bw,
                                                   unsigned short* __restrict__ pb) {
  __shared__ float lg[16 * LGS];
  const int n = blockIdx.x;
  const int tid = threadIdx.x;
  const int wv = tid >> 6, lane = tid & 63;
  const int l15 = lane & 15, kg = lane >> 4;
  const bool buffered = (n < NRIDE);

  if (!buffered) {
#define LOADCH(X, CH) do {                                                        \
    const float* xp_ = pair_rep + ((size_t)n * NTOK + (CH) * 16 + l15) * PD + kg * 8; \
    _Pragma("unroll")                                                             \
    for (int q_ = 0; q_ < 4; ++q_) {                                              \
      X[q_ * 2]     = *(const float4*)(xp_ + q_ * 32);                            \
      X[q_ * 2 + 1] = *(const float4*)(xp_ + q_ * 32 + 4);                        \
    }                                                                             \
  } while (0)

    float4 Xa[8], Xb[8];
    LOADCH(Xa, wv);
    LOADCH(Xb, wv + 4);

    short8 bh[4], bl[4];
#pragma unroll
    for (int ks = 0; ks < 4; ++ks)
#pragma unroll
      for (int j = 0; j < 8; ++j) {
        int p = ks * 32 + kg * 8 + j;
        bh[ks][j] = (short)gw_hi[p * 16 + l15];
        bl[ks][j] = (short)gw_lo[p * 16 + l15];
      }
    float sgv[4], bwv[4];
#pragma unroll
    for (int r = 0; r < 4; ++r) { sgv[r] = sgw[kg * 4 + r]; bwv[r] = bw[kg * 4 + r]; }

#define PROC(X, CH) do {                                                          \
    float sum_ = 0.f, sq_ = 0.f;                                                  \
    _Pragma("unroll")                                                             \
    for (int q_ = 0; q_ < 8; ++q_) {                                              \
      sum_ += X[q_].x + X[q_].y + X[q_].z + X[q_].w;                              \
      sq_ = fmaf(X[q_].x, X[q_].x, sq_); sq_ = fmaf(X[q_].y, X[q_].y, sq_);       \
      sq_ = fmaf(X[q_].z, X[q_].z, sq_); sq_ = fmaf(X[q_].w, X[q_].w, sq_);       \
    }                                                                             \
    sum_ += __shfl_xor(sum_, 16); sum_ += __shfl_xor(sum_, 32);                   \
    sq_  += __shfl_xor(sq_, 16);  sq_  += __shfl_xor(sq_, 32);                    \
    float mu_ = sum_ * (1.f / 128.f);                                             \
    float rstd_ = rsqrtf(sq_ * (1.f / 128.f) - mu_ * mu_ + 1e-5f);                \
    f32x4 acc_ = {0.f, 0.f, 0.f, 0.f};                                            \
    _Pragma("unroll")                                                             \
    for (int ks_ = 0; ks_ < 4; ++ks_) {                                           \
      float4 u0_ = X[ks_ * 2], u1_ = X[ks_ * 2 + 1];                              \
      unsigned p0_ = cvtpk(u0_.x, u0_.y), p1_ = cvtpk(u0_.z, u0_.w);              \
      unsigned p2_ = cvtpk(u1_.x, u1_.y), p3_ = cvtpk(u1_.z, u1_.w);              \
      float l0_ = u0_.x - lo2f(p0_), l1_ = u0_.y - hi2f(p0_);                     \
      float l2_ = u0_.z - lo2f(p1_), l3_ = u0_.w - hi2f(p1_);                     \
      float l4_ = u1_.x - lo2f(p2_), l5_ = u1_.y - hi2f(p2_);                     \
      float l6_ = u1_.z - lo2f(p3_), l7_ = u1_.w - hi2f(p3_);                     \
      unsigned q0_ = cvtpk(l0_, l1_), q1_ = cvtpk(l2_, l3_);                      \
      unsigned q2_ = cvtpk(l4_, l5_), q3_ = cvtpk(l6_, l7_);                      \
      u32x4 hp_ = {p0_, p1_, p2_, p3_}, lp_ = {q0_, q1_, q2_, q3_};               \
      short8 ah_ = __builtin_bit_cast(short8, hp_);                               \
      short8 al_ = __builtin_bit_cast(short8, lp_);                               \
      acc_ = __builtin_amdgcn_mfma_f32_16x16x32_bf16(bh[ks_], ah_, acc_, 0, 0, 0);\
      acc_ = __builtin_amdgcn_mfma_f32_16x16x32_bf16(bh[ks_], al_, acc_, 0, 0, 0);\
      acc_ = __builtin_amdgcn_mfma_f32_16x16x32_bf16(bl[ks_], ah_, acc_, 0, 0, 0);\
    }                                                                             \
    _Pragma("unroll")                                                             \
    for (int r_ = 0; r_ < 4; ++r_) {                                              \
      float val_ = rstd_ * (acc_[r_] - mu_ * sgv[r_]) + bwv[r_];                  \
      lg[(kg * 4 + r_) * LGS + (CH) * 16 + l15] = val_;                           \
    }                                                                             \
  } while (0)

    PROC(Xa, wv +  0); LOADCH(Xa, wv +  8);
    PROC(Xb, wv +  4); LOADCH(Xb, wv + 12);
    PROC(Xa, wv +  8); LOADCH(Xa, wv + 16);
    PROC(Xb, wv + 12); LOADCH(Xb, wv + 20);
    PROC(Xa, wv + 16); LOADCH(Xa, wv + 24);
    PROC(Xb, wv + 20); LOADCH(Xb, wv + 28);
    PROC(Xa, wv + 24); LOADCH(Xa, wv + 32);
    PROC(Xb, wv + 28); LOADCH(Xb, wv + 36);
    PROC(Xa, wv + 32); LOADCH(Xa, wv + 40);
    PROC(Xb, wv + 36); LOADCH(Xb, wv + 44);
    PROC(Xa, wv + 40);
    PROC(Xb, wv + 44);
#undef LOADCH
#undef PROC
    __syncthreads();
  }

#pragma unroll
  for (int hh = 0; hh < 4; ++hh) {
    int h = wv * 4 + hh;
    const float* qrow = qkl + ((size_t)n * NH + h) * NTOK;
    const float* brow = biasBuf + ((size_t)n * NH + h) * NTOK;
    float x[12];
    if (buffered) {
#pragma unroll
      for (int i = 0; i < 12; ++i) x[i] = brow[lane + 64 * i] + qrow[lane + 64 * i];
    } else {
#pragma unroll
      for (int i = 0; i < 12; ++i) x[i] = lg[h * LGS + lane + 64 * i] + qrow[lane + 64 * i];
    }
    float mx = x[0];
#pragma unroll
    for (int t = 1; t < 12; ++t) mx = fmaxf(mx, x[t]);
#pragma unroll
    for (int off = 1; off < 64; off <<= 1) mx = fmaxf(mx, __shfl_xor(mx, off));
    float e[12], sm = 0.f;
#pragma unroll
    for (int t = 0; t < 12; ++t) { e[t] = __expf(x[t] - mx); sm += e[t]; }
#pragma unroll
    for (int off = 1; off < 64; off <<= 1) sm += __shfl_xor(sm, off);
    float inv = 1.0f / sm;
    unsigned short* dst = pb + ((size_t)h * NTOK + n) * NTOK;
#pragma unroll
    for (int i = 0; i < 12; ++i) dst[lane + 64 * i] = f2bf(e[i] * inv);
  }
}

// ---------------- PV: attn*gate -> ag hi/lo bf16 (double-buffered) ----------------
__global__ __launch_bounds__(256) void k_pv(const unsigned short* __restrict__ wb,
                                            const unsigned short* __restrict__ vT,
                                            const float* __restrict__ gbuf,
                                            unsigned short* __restrict__ agh,
                                            unsigned short* __restrict__ agl) {
  const int ntile = blockIdx.x, h = blockIdx.y;
  const int n0 = ntile * 64;
  __shared__ unsigned short wsm[2][64 * 40];
  __shared__ unsigned short vtm[2][48 * 40];
  const int tid = threadIdx.x;
  const int wv = tid >> 6, lane = tid & 63, l15 = lane & 15, kg = lane >> 4;
  const int srow = tid >> 2, sc = tid & 3;
  const unsigned short* wsrc = wb + ((size_t)h * NTOK + (n0 + srow)) * NTOK + sc * 8;
  const unsigned short* vsrc = (tid < 192)
      ? vT + (size_t)(h * DH + srow) * NTOK + sc * 8 : nullptr;
  f32x4 acc[3];
#pragma unroll
  for (int dt = 0; dt < 3; ++dt) acc[dt] = (f32x4){0.f, 0.f, 0.f, 0.f};

  *(u16x8*)(wsm[0] + srow * 40 + sc * 8) = *(const u16x8*)(wsrc);
  if (tid < 192)
    *(u16x8*)(vtm[0] + srow * 40 + sc * 8) = *(const u16x8*)(vsrc);
  __syncthreads();

  int buf = 0;
  for (int k0 = 0; k0 < NTOK; k0 += 32) {
    if (k0 + 32 < NTOK) {
      *(u16x8*)(wsm[buf ^ 1] + srow * 40 + sc * 8) = *(const u16x8*)(wsrc + k0 + 32);
      if (tid < 192)
        *(u16x8*)(vtm[buf ^ 1] + srow * 40 + sc * 8) = *(const u16x8*)(vsrc + k0 + 32);
    }
    short8 av = *(const short8*)(wsm[buf] + (wv * 16 + l15) * 40 + kg * 8);
#pragma unroll
    for (int dt = 0; dt < 3; ++dt) {
      short8 bv = *(const short8*)(vtm[buf] + (dt * 16 + l15) * 40 + kg * 8);
      acc[dt] = __builtin_amdgcn_mfma_f32_16x16x32_bf16(av, bv, acc[dt], 0, 0, 0);
    }
    __syncthreads();
    buf ^= 1;
  }
#pragma unroll
  for (int dt = 0; dt < 3; ++dt)
#pragma unroll
    for (int r = 0; r < 4; ++r) {
      int nn = n0 + wv * 16 + kg * 4 + r;
      int col = h * DH + dt * 16 + l15;
      size_t idx = (size_t)nn * ED + col;
      float val = acc[dt][r] * gbuf[idx];
      unsigned short hb = f2bf(val);
      agh[idx] = hb;
      agl[idx] = f2bf(val - bf2f(hb));
    }
}

extern "C" void kernel_launch(void* const* d_in, const int* in_sizes, int n_in,
                              void* d_out, int out_size, void* d_ws, size_t ws_size,
                              hipStream_t stream) {
  const float* a    = (const float*)d_in[0];
  const float* s    = (const float*)d_in[1];
  const float* pair = (const float*)d_in[2];
  const float* beta = (const float*)d_in[3];
  const float* wag  = (const float*)d_in[4];
  const float* wab  = (const float*)d_in[5];
  const float* wq   = (const float*)d_in[6];
  const float* bq   = (const float*)d_in[7];
  const float* wk   = (const float*)d_in[8];
  const float* wvp  = (const float*)d_in[9];
  const float* lng  = (const float*)d_in[10];
  const float* lnb  = (const float*)d_in[11];
  const float* wpair= (const float*)d_in[12];
  const float* wg   = (const float*)d_in[13];
  const float* wproj= (const float*)d_in[14];
  const float* wo   = (const float*)d_in[15];
  const float* bo   = (const float*)d_in[16];
  float* out = (float*)d_out;

  if (ws_size < WS_NEED) return;

  char* ws = (char*)d_ws;
  unsigned short* snh  = (unsigned short*)(ws + OFF_SNH);
  unsigned short* snl  = (unsigned short*)(ws + OFF_SNL);
  unsigned short* srh  = (unsigned short*)(ws + OFF_SRH);
  unsigned short* srl  = (unsigned short*)(ws + OFF_SRL);
  float*          gaml = (float*)(ws + OFF_GAM);
  float*          betl = (float*)(ws + OFF_BET);
  float*          og   = (float*)(ws + OFF_OG);
  unsigned short* amh  = (unsigned short*)(ws + OFF_AMH);
  unsigned short* aml  = (unsigned short*)(ws + OFF_AML);
  unsigned short* qb   = (unsigned short*)(ws + OFF_QB);
  unsigned short* kb   = (unsigned short*)(ws + OFF_KB);
  unsigned short* vT   = (unsigned short*)(ws + OFF_VT);
  float*          gbuf = (float*)(ws + OFF_GBUF);
  unsigned short* agh  = (unsigned short*)(ws + OFF_AGH);
  unsigned short* agl  = (unsigned short*)(ws + OFF_AGL);
  unsigned short* wsmh = (unsigned short*)(ws + OFF_WSMH);
  unsigned short* wsml = (unsigned short*)(ws + OFF_WSML);
  unsigned short* wqh  = (unsigned short*)(ws + OFF_WQH);
  unsigned short* wql  = (unsigned short*)(ws + OFF_WQL);
  unsigned short* wph  = (unsigned short*)(ws + OFF_WPH);
  unsigned short* wpl  = (unsigned short*)(ws + OFF_WPL);
  unsigned short* gwh  = (unsigned short*)(ws + OFF_GWH);
  unsigned short* gwl  = (unsigned short*)(ws + OFF_GWL);
  float*          sgw  = (float*)(ws + OFF_SGW);
  float*          bw   = sgw + 16;
  float*          qkl  = (float*)(ws + OFF_QKL);
  unsigned short* pb   = (unsigned short*)(ws + OFF_PB);
  float*          bb   = (float*)(ws + OFF_BB);

  hipLaunchKernelGGL(k_wcvt, dim3(24, 24, 9), dim3(256), 0, stream,
                     wag, wab, wo, wq, wk, wvp, wg, wproj, lng, lnb, wpair, s,
                     wsmh, wsml, wqh, wql, wph, wpl, gwh, gwl, sgw, bw,
                     snh, snl, srh, srl);
  hipLaunchKernelGGL(k_gemm_small, dim3(36, 12), dim3(256), 0, stream,
                     snh, snl, srh, srl, wsmh, wsml, bo, gaml, betl, og);
  hipLaunchKernelGGL(k_amod, dim3(768), dim3(256), 0, stream, a, gaml, betl, amh, aml);
  hipLaunchKernelGGL(k_gemm_qkvg, dim3(48, 16), dim3(256), 0, stream,
                     amh, aml, wqh, wql, bq, pair, gwh, gwl, sgw, bw, bb,
                     qb, kb, vT, gbuf);
  hipLaunchKernelGGL(k_qkw, dim3(12, 12, 16), dim3(256), 0, stream, qb, kb, beta, qkl);
  hipLaunchKernelGGL(k_pairsm, dim3(768), dim3(256), 0, stream,
                     pair, qkl, bb, gwh, gwl, sgw, bw, pb);
  hipLaunchKernelGGL(k_pv, dim3(12, 16), dim3(256), 0, stream, pb, vT, gbuf, agh, agl);
  hipLaunchKernelGGL(k_gemm_proj, dim3(12, 12), dim3(256), 0, stream,
                     agh, agl, wph, wpl, og, out);
}

// Round 18
// 171.507 us; speedup vs baseline: 1.0953x; 1.0504x over previous
//
#include <hip/hip_runtime.h>
#include <hip/hip_bf16.h>

typedef __attribute__((ext_vector_type(8))) short short8;
typedef __attribute__((ext_vector_type(8))) unsigned short u16x8;
typedef __attribute__((ext_vector_type(4))) unsigned short u16x4;
typedef __attribute__((ext_vector_type(4))) float f32x4;
typedef __attribute__((ext_vector_type(4))) unsigned u32x4;

#define NTOK 768
#define ED   768
#define SD   384
#define PD   128
#define NH   16
#define DH   48
#define LGS  778

__device__ __forceinline__ unsigned short f2bf(float x) {
  unsigned u = __builtin_bit_cast(unsigned, x);
  u += 0x7FFFu + ((u >> 16) & 1u);
  return (unsigned short)(u >> 16);
}
__device__ __forceinline__ float bf2f(unsigned short b) {
  unsigned u = ((unsigned)b) << 16;
  return __builtin_bit_cast(float, u);
}
__device__ __forceinline__ float sigm(float x) { return 1.0f / (1.0f + __expf(-x)); }

__device__ __forceinline__ unsigned cvtpk(float a, float b) {
  unsigned r;
  asm("v_cvt_pk_bf16_f32 %0, %1, %2" : "=v"(r) : "v"(a), "v"(b));
  return r;
}
__device__ __forceinline__ float lo2f(unsigned p) {
  return __builtin_bit_cast(float, p << 16);
}
__device__ __forceinline__ float hi2f(unsigned p) {
  return __builtin_bit_cast(float, p & 0xFFFF0000u);
}

__device__ __forceinline__ void gl2lds(const unsigned short* g, unsigned short* l) {
  __builtin_amdgcn_global_load_lds(
      (const __attribute__((address_space(1))) unsigned int*)g,
      (__attribute__((address_space(3))) unsigned int*)l, 16, 0, 0);
}

// ---------------- workspace layout (bytes) ----------------
constexpr size_t SZ_SN   = (size_t)NTOK * SD * 2;
constexpr size_t OFF_SNH = 0;
constexpr size_t OFF_SNL = OFF_SNH + SZ_SN;
constexpr size_t OFF_SRH = OFF_SNL + SZ_SN;
constexpr size_t OFF_SRL = OFF_SRH + SZ_SN;
constexpr size_t OFF_GAM = OFF_SRL + SZ_SN;                // f32 [768][768]
constexpr size_t OFF_BET = OFF_GAM + 2359296;
constexpr size_t OFF_OG  = OFF_BET + 2359296;
constexpr size_t OFF_AMH = OFF_OG  + 2359296;              // bf16 [768][768]
constexpr size_t OFF_AML = OFF_AMH + 1179648;
constexpr size_t OFF_QB  = OFF_AML + 1179648;
constexpr size_t OFF_KB  = OFF_QB  + 1179648;
constexpr size_t OFF_VT  = OFF_KB  + 1179648;              // bf16 [768 hd][768 m]
constexpr size_t OFF_GBUF= OFF_VT  + 1179648;              // f32
constexpr size_t OFF_AGH = OFF_GBUF+ 2359296;
constexpr size_t OFF_AGL = OFF_AGH + 1179648;
constexpr size_t OFF_WSMH= OFF_AGL + 1179648;              // [2304][384] bf16
constexpr size_t OFF_WSML= OFF_WSMH+ 1769472;
constexpr size_t OFF_WQH = OFF_WSML+ 1769472;              // [3072][768] bf16
constexpr size_t OFF_WQL = OFF_WQH + 4718592;
constexpr size_t OFF_WPH = OFF_WQL + 4718592;              // [768][768] bf16
constexpr size_t OFF_WPL = OFF_WPH + 1179648;
constexpr size_t OFF_GWH = OFF_WPL + 1179648;
constexpr size_t OFF_GWL = OFF_GWH + 4096;
constexpr size_t OFF_SGW = OFF_GWL + 4096;
constexpr size_t OFF_QKL = OFF_SGW + 4096;                 // f32 [768 n][16 h][768 m]
constexpr size_t OFF_PB  = OFF_QKL + 37748736;             // bf16 [16 h][768 n][768 m]
constexpr size_t WS_NEED = OFF_PB  + 18874368;

// ---------------- preprocessing: weights + setup + LN(s) ----------------
__global__ __launch_bounds__(256) void k_wcvt(
    const float* __restrict__ wag, const float* __restrict__ wab, const float* __restrict__ wo,
    const float* __restrict__ wq, const float* __restrict__ wk, const float* __restrict__ wv,
    const float* __restrict__ wg, const float* __restrict__ wp,
    const float* __restrict__ lng, const float* __restrict__ lnb,
    const float* __restrict__ wpair, const float* __restrict__ s,
    unsigned short* __restrict__ wsmh, unsigned short* __restrict__ wsml,
    unsigned short* __restrict__ wqh, unsigned short* __restrict__ wql,
    unsigned short* __restrict__ wph, unsigned short* __restrict__ wpl,
    unsigned short* __restrict__ gwh, unsigned short* __restrict__ gwl,
    float* __restrict__ sgw, float* __restrict__ bw,
    unsigned short* __restrict__ snh, unsigned short* __restrict__ snl,
    unsigned short* __restrict__ srh, unsigned short* __restrict__ srl) {
  const int tid = threadIdx.x;
  if (blockIdx.z == 8) {
    const int gid = blockIdx.y * 24 + blockIdx.x;
    if (gid == 192) {
      if (tid < 128) {
        float g = lng[tid];
        for (int hh = 0; hh < 16; ++hh) {
          float gwv = g * wpair[tid * 16 + hh];
          unsigned short hb = f2bf(gwv);
          gwh[tid * 16 + hh] = hb;
          gwl[tid * 16 + hh] = f2bf(gwv - bf2f(hb));
        }
      }
      if (tid < 16) {
        float sv = 0.f, bb = 0.f;
        for (int p = 0; p < 128; ++p) {
          float w = wpair[p * 16 + tid];
          sv += lng[p] * w;
          bb += lnb[p] * w;
        }
        sgw[tid] = sv;
        bw[tid]  = bb;
      }
      return;
    }
    if (gid > 192) return;
    const int n = gid * 4 + (tid >> 6);
    const int lane = tid & 63;
    const float* row = s + (size_t)n * SD;
    float v[6], sum = 0.f, sq = 0.f;
#pragma unroll
    for (int i = 0; i < 6; ++i) { v[i] = row[lane + 64 * i]; sum += v[i]; sq += v[i] * v[i]; }
#pragma unroll
    for (int off = 1; off < 64; off <<= 1) { sum += __shfl_xor(sum, off); sq += __shfl_xor(sq, off); }
    float mu = sum * (1.f / SD);
    float var = sq * (1.f / SD) - mu * mu;
    float rs = rsqrtf(var + 1e-5f);
#pragma unroll
    for (int i = 0; i < 6; ++i) {
      size_t idx = (size_t)n * SD + lane + 64 * i;
      float x = v[i];
      unsigned short xh = f2bf(x);
      srh[idx] = xh; srl[idx] = f2bf(x - bf2f(xh));
      float y = (x - mu) * rs;
      unsigned short yh = f2bf(y);
      snh[idx] = yh; snl[idx] = f2bf(y - bf2f(yh));
    }
    return;
  }
  const int id = blockIdx.z;
  const float* src; int Ksrc; unsigned short *dh, *dl; int n0; int Kd;
  switch (id) {
    case 0: src = wag; Ksrc = 384; dh = wsmh; dl = wsml; n0 = 0;    Kd = 384; break;
    case 1: src = wab; Ksrc = 384; dh = wsmh; dl = wsml; n0 = 768;  Kd = 384; break;
    case 2: src = wo;  Ksrc = 384; dh = wsmh; dl = wsml; n0 = 1536; Kd = 384; break;
    case 3: src = wq;  Ksrc = 768; dh = wqh;  dl = wql;  n0 = 0;    Kd = 768; break;
    case 4: src = wk;  Ksrc = 768; dh = wqh;  dl = wql;  n0 = 768;  Kd = 768; break;
    case 5: src = wv;  Ksrc = 768; dh = wqh;  dl = wql;  n0 = 1536; Kd = 768; break;
    case 6: src = wg;  Ksrc = 768; dh = wqh;  dl = wql;  n0 = 2304; Kd = 768; break;
    default: src = wp; Ksrc = 768; dh = wph;  dl = wpl;  n0 = 0;    Kd = 768; break;
  }
  const int kt = blockIdx.x, ntile = blockIdx.y;
  if (kt * 32 >= Ksrc) return;
  __shared__ float t[32][33];
  const int r = tid >> 3, c4 = (tid & 7) * 4;
  float4 v = *(const float4*)(src + (size_t)(kt * 32 + r) * 768 + ntile * 32 + c4);
  t[r][c4 + 0] = v.x; t[r][c4 + 1] = v.y; t[r][c4 + 2] = v.z; t[r][c4 + 3] = v.w;
  __syncthreads();
  u16x4 hv, lv;
#pragma unroll
  for (int j = 0; j < 4; ++j) {
    float x = t[c4 + j][r];
    unsigned short hb = f2bf(x);
    hv[j] = hb;
    lv[j] = f2bf(x - bf2f(hb));
  }
  size_t drow = (size_t)(n0 + ntile * 32 + r) * Kd + kt * 32 + c4;
  *(u16x4*)(dh + drow) = hv;
  *(u16x4*)(dl + drow) = lv;
}

// ---------------- split-bf16 MFMA GEMM core: 64x64 tile, 256 threads ----------------
__device__ __forceinline__ void mfma_core(
    const unsigned short* __restrict__ Ah, const unsigned short* __restrict__ Al,
    const unsigned short* __restrict__ Bh, const unsigned short* __restrict__ Bl,
    int K, int mBase, int nBase, f32x4 acc[2][2]) {
  __shared__ unsigned short lds[2][4][4096];
  const int tid = threadIdx.x;
  const int w = tid >> 6, lane = tid & 63;
  const int l15 = lane & 15, kg = lane >> 4;
  const int wr = w >> 1, wc = w & 1;

  size_t offA[2], offB[2];
  int ldsw[2];
#pragma unroll
  for (int i = 0; i < 2; ++i) {
    int chunk = w * 128 + i * 64 + lane;
    int row = chunk >> 3;
    int slot = (chunk & 7) ^ (row & 7);
    offA[i] = (size_t)(mBase + row) * K + slot * 8;
    offB[i] = (size_t)(nBase + row) * K + slot * 8;
    ldsw[i] = w * 1024 + i * 512;
  }
  auto stage = [&](int b, int k0) {
#pragma unroll
    for (int i = 0; i < 2; ++i) {
      gl2lds(Ah + offA[i] + k0, &lds[b][0][ldsw[i]]);
      gl2lds(Al + offA[i] + k0, &lds[b][1][ldsw[i]]);
      gl2lds(Bh + offB[i] + k0, &lds[b][2][ldsw[i]]);
      gl2lds(Bl + offB[i] + k0, &lds[b][3][ldsw[i]]);
    }
  };

  stage(0, 0);
  int buf = 0;
  for (int k0 = 64; k0 <= K; k0 += 64) {
    __syncthreads();
    if (k0 < K) stage(buf ^ 1, k0);
#pragma unroll
    for (int kk = 0; kk < 2; ++kk) {
      short8 ah[2], al[2], bh4[2], bl4[2];
#pragma unroll
      for (int mi = 0; mi < 2; ++mi) {
        int row = wr * 32 + mi * 16 + l15;
        int kb = kk * 64 + kg * 16;
        int idx = row * 64 + ((kb ^ ((row & 7) << 4)) >> 1);
        ah[mi] = *(const short8*)&lds[buf][0][idx];
        al[mi] = *(const short8*)&lds[buf][1][idx];
      }
#pragma unroll
      for (int ni = 0; ni < 2; ++ni) {
        int row = wc * 32 + ni * 16 + l15;
        int kb = kk * 64 + kg * 16;
        int idx = row * 64 + ((kb ^ ((row & 7) << 4)) >> 1);
        bh4[ni] = *(const short8*)&lds[buf][2][idx];
        bl4[ni] = *(const short8*)&lds[buf][3][idx];
      }
#pragma unroll
      for (int mi = 0; mi < 2; ++mi)
#pragma unroll
        for (int ni = 0; ni < 2; ++ni) {
          acc[mi][ni] = __builtin_amdgcn_mfma_f32_16x16x32_bf16(ah[mi], bh4[ni], acc[mi][ni], 0, 0, 0);
          acc[mi][ni] = __builtin_amdgcn_mfma_f32_16x16x32_bf16(al[mi], bh4[ni], acc[mi][ni], 0, 0, 0);
          acc[mi][ni] = __builtin_amdgcn_mfma_f32_16x16x32_bf16(ah[mi], bl4[ni], acc[mi][ni], 0, 0, 0);
        }
    }
    buf ^= 1;
  }
}

// ---------------- GEMM instances (64x64 tiles, 256-thread blocks) ----------------
__global__ __launch_bounds__(256) void k_gemm_small(
    const unsigned short* __restrict__ snh, const unsigned short* __restrict__ snl,
    const unsigned short* __restrict__ srh, const unsigned short* __restrict__ srl,
    const unsigned short* __restrict__ wsmh, const unsigned short* __restrict__ wsml,
    const float* __restrict__ bo,
    float* __restrict__ gaml, float* __restrict__ betl, float* __restrict__ og) {
  const int nt = blockIdx.x, mt = blockIdx.y;
  const unsigned short* Ah = (nt < 24) ? snh : srh;
  const unsigned short* Al = (nt < 24) ? snl : srl;
  f32x4 acc[2][2];
#pragma unroll
  for (int i = 0; i < 2; ++i)
#pragma unroll
    for (int j = 0; j < 2; ++j) acc[i][j] = (f32x4){0.f, 0.f, 0.f, 0.f};
  mfma_core(Ah, Al, wsmh, wsml, SD, mt * 64, nt * 64, acc);
  const int tid = threadIdx.x;
  const int w = tid >> 6, lane = tid & 63;
  const int l15 = lane & 15, kg = lane >> 4;
  const int wr = w >> 1, wc = w & 1;
#pragma unroll
  for (int mi = 0; mi < 2; ++mi)
#pragma unroll
    for (int ni = 0; ni < 2; ++ni) {
      int col = nt * 64 + wc * 32 + ni * 16 + l15;
#pragma unroll
      for (int r = 0; r < 4; ++r) {
        int row = mt * 64 + wr * 32 + mi * 16 + kg * 4 + r;
        float v = acc[mi][ni][r];
        if (col < 768) gaml[(size_t)row * ED + col] = v;
        else if (col < 1536) betl[(size_t)row * ED + col - 768] = v;
        else og[(size_t)row * ED + col - 1536] = sigm(v + bo[col - 1536]);
      }
    }
}

__global__ __launch_bounds__(256) void k_gemm_qkvg(
    const unsigned short* __restrict__ amh, const unsigned short* __restrict__ aml,
    const unsigned short* __restrict__ wqh, const unsigned short* __restrict__ wql,
    const float* __restrict__ bq,
    unsigned short* __restrict__ qb, unsigned short* __restrict__ kb,
    unsigned short* __restrict__ vT, float* __restrict__ gbuf) {
  const int nt = blockIdx.x, mt = blockIdx.y;
  f32x4 acc[2][2];
#pragma unroll
  for (int i = 0; i < 2; ++i)
#pragma unroll
    for (int j = 0; j < 2; ++j) acc[i][j] = (f32x4){0.f, 0.f, 0.f, 0.f};
  mfma_core(amh, aml, wqh, wql, ED, mt * 64, nt * 64, acc);
  const int tid = threadIdx.x;
  const int w = tid >> 6, lane = tid & 63;
  const int l15 = lane & 15, kg = lane >> 4;
  const int wr = w >> 1, wc = w & 1;
  const int sel = nt / 12;
#pragma unroll
  for (int mi = 0; mi < 2; ++mi)
#pragma unroll
    for (int ni = 0; ni < 2; ++ni) {
      int col = nt * 64 + wc * 32 + ni * 16 + l15;
      int c = col - sel * 768;
#pragma unroll
      for (int r = 0; r < 4; ++r) {
        int row = mt * 64 + wr * 32 + mi * 16 + kg * 4 + r;
        float v = acc[mi][ni][r];
        size_t idx = (size_t)row * ED + c;
        if (sel == 0) qb[idx] = f2bf(v + bq[c]);
        else if (sel == 1) kb[idx] = f2bf(v);
        else if (sel == 2) vT[(size_t)c * NTOK + row] = f2bf(v);
        else gbuf[idx] = sigm(v);
      }
    }
}

__global__ __launch_bounds__(256) void k_gemm_proj(
    const unsigned short* __restrict__ agh, const unsigned short* __restrict__ agl,
    const unsigned short* __restrict__ wph, const unsigned short* __restrict__ wpl,
    const float* __restrict__ og, float* __restrict__ out) {
  const int nt = blockIdx.x, mt = blockIdx.y;
  f32x4 acc[2][2];
#pragma unroll
  for (int i = 0; i < 2; ++i)
#pragma unroll
    for (int j = 0; j < 2; ++j) acc[i][j] = (f32x4){0.f, 0.f, 0.f, 0.f};
  mfma_core(agh, agl, wph, wpl, ED, mt * 64, nt * 64, acc);
  const int tid = threadIdx.x;
  const int w = tid >> 6, lane = tid & 63;
  const int l15 = lane & 15, kg = lane >> 4;
  const int wr = w >> 1, wc = w & 1;
#pragma unroll
  for (int mi = 0; mi < 2; ++mi)
#pragma unroll
    for (int ni = 0; ni < 2; ++ni) {
      int col = nt * 64 + wc * 32 + ni * 16 + l15;
#pragma unroll
      for (int r = 0; r < 4; ++r) {
        int row = mt * 64 + wr * 32 + mi * 16 + kg * 4 + r;
        size_t idx = (size_t)row * ED + col;
        out[idx] = acc[mi][ni][r] * og[idx];
      }
    }
}

// ---------------- AdaLN combine -> a_mod hi/lo bf16 ----------------
__global__ __launch_bounds__(256) void k_amod(const float* __restrict__ a,
                                              const float* __restrict__ gamma_lin,
                                              const float* __restrict__ beta_lin,
                                              unsigned short* __restrict__ amh,
                                              unsigned short* __restrict__ aml) {
  __shared__ float red[8];
  const int n = blockIdx.x, tid = threadIdx.x;
  const int lane = tid & 63, wid = tid >> 6;
  const float* row = a + (size_t)n * ED;
  float v[3], sum = 0.f, sq = 0.f;
#pragma unroll
  for (int i = 0; i < 3; ++i) { v[i] = row[tid + 256 * i]; sum += v[i]; sq += v[i] * v[i]; }
#pragma unroll
  for (int off = 1; off < 64; off <<= 1) { sum += __shfl_xor(sum, off); sq += __shfl_xor(sq, off); }
  if (lane == 0) { red[wid] = sum; red[4 + wid] = sq; }
  __syncthreads();
  float S = red[0] + red[1] + red[2] + red[3];
  float Q = red[4] + red[5] + red[6] + red[7];
  float mu = S * (1.f / ED);
  float var = Q * (1.f / ED) - mu * mu;
  float rs = rsqrtf(var + 1e-5f);
#pragma unroll
  for (int i = 0; i < 3; ++i) {
    int e = tid + 256 * i;
    float an = (v[i] - mu) * rs;
    size_t idx = (size_t)n * ED + e;
    float val = sigm(gamma_lin[idx]) * an + beta_lin[idx];
    unsigned short h = f2bf(val);
    amh[idx] = h;
    aml[idx] = f2bf(val - bf2f(h));
  }
}

// ---------------- QK^T -> qkl[n][h][m] = q.k^T*scale + beta ----------------
__global__ __launch_bounds__(256) void k_qkw(const unsigned short* __restrict__ qb,
                                             const unsigned short* __restrict__ kb,
                                             const float* __restrict__ beta,
                                             float* __restrict__ qkl) {
  const int mt = blockIdx.x, ntile = blockIdx.y, h = blockIdx.z;
  __shared__ unsigned short qs[64 * 72];
  __shared__ unsigned short ksm[64 * 72];
  const int tid = threadIdx.x;
  const int n0 = ntile * 64, m0 = mt * 64;
  const u16x8 z = {0, 0, 0, 0, 0, 0, 0, 0};
#pragma unroll
  for (int it = 0; it < 2; ++it) {
    int idx = tid + it * 256;
    int row = idx >> 3, c = idx & 7;
    u16x8 vq = z, vk = z;
    if (c < 6) {
      vq = *(const u16x8*)(qb + (size_t)(n0 + row) * ED + h * DH + c * 8);
      vk = *(const u16x8*)(kb + (size_t)(m0 + row) * ED + h * DH + c * 8);
    }
    *(u16x8*)(qs + row * 72 + c * 8) = vq;
    *(u16x8*)(ksm + row * 72 + c * 8) = vk;
  }
  __syncthreads();
  const int wv = tid >> 6, lane = tid & 63;
  const int l15 = lane & 15, kg = lane >> 4;
  f32x4 acc[4];
#pragma unroll
  for (int ct = 0; ct < 4; ++ct) acc[ct] = (f32x4){0.f, 0.f, 0.f, 0.f};
#pragma unroll
  for (int ks2 = 0; ks2 < 2; ++ks2) {
    short8 av = *(const short8*)(qs + (wv * 16 + l15) * 72 + ks2 * 32 + kg * 8);
#pragma unroll
    for (int ct = 0; ct < 4; ++ct) {
      short8 bv = *(const short8*)(ksm + (ct * 16 + l15) * 72 + ks2 * 32 + kg * 8);
      acc[ct] = __builtin_amdgcn_mfma_f32_16x16x32_bf16(av, bv, acc[ct], 0, 0, 0);
    }
  }
  const float scale = 0.14433756729740643f;
#pragma unroll
  for (int ct = 0; ct < 4; ++ct)
#pragma unroll
    for (int r = 0; r < 4; ++r) {
      int nn = n0 + wv * 16 + kg * 4 + r;
      int mm = m0 + ct * 16 + l15;
      qkl[((size_t)nn * NH + h) * NTOK + mm] =
          fmaf(acc[ct][r], scale, beta[(size_t)nn * NTOK + mm]);
    }
}

// ---------------- fused pair bias + softmax -> P bf16 [h][n][m] ----------------
__global__ __launch_bounds__(256, 3) void k_pairsm(const float* __restrict__ pair_rep,
                                                   const float* __restrict__ qkl,
                                                   const unsigned short* __restrict__ gw_hi,
                                                   const unsigned short* __restrict__ gw_lo,
                                                   const float* __restrict__ sgw, const float* __restrict__ bw,
                                                   unsigned short* __restrict__ pb) {
  __shared__ float lg[16 * LGS];
  const int n = blockIdx.x;
  const int tid = threadIdx.x;
  const int wv = tid >> 6, lane = tid & 63;
  const int l15 = lane & 15, kg = lane >> 4;

#define LOADCH(X, CH) do {                                                        \
    const float* xp_ = pair_rep + ((size_t)n * NTOK + (CH) * 16 + l15) * PD + kg * 8; \
    _Pragma("unroll")                                                             \
    for (int q_ = 0; q_ < 4; ++q_) {                                              \
      X[q_ * 2]     = *(const float4*)(xp_ + q_ * 32);                            \
      X[q_ * 2 + 1] = *(const float4*)(xp_ + q_ * 32 + 4);                        \
    }                                                                             \
  } while (0)

  float4 Xa[8], Xb[8];
  LOADCH(Xa, wv);
  LOADCH(Xb, wv + 4);

  short8 bh[4], bl[4];
#pragma unroll
  for (int ks = 0; ks < 4; ++ks)
#pragma unroll
    for (int j = 0; j < 8; ++j) {
      int p = ks * 32 + kg * 8 + j;
      bh[ks][j] = (short)gw_hi[p * 16 + l15];
      bl[ks][j] = (short)gw_lo[p * 16 + l15];
    }
  float sgv[4], bwv[4];
#pragma unroll
  for (int r = 0; r < 4; ++r) { sgv[r] = sgw[kg * 4 + r]; bwv[r] = bw[kg * 4 + r]; }

#define PROC(X, CH) do {                                                          \
    float sum_ = 0.f, sq_ = 0.f;                                                  \
    _Pragma("unroll")                                                             \
    for (int q_ = 0; q_ < 8; ++q_) {                                              \
      sum_ += X[q_].x + X[q_].y + X[q_].z + X[q_].w;                              \
      sq_ = fmaf(X[q_].x, X[q_].x, sq_); sq_ = fmaf(X[q_].y, X[q_].y, sq_);       \
      sq_ = fmaf(X[q_].z, X[q_].z, sq_); sq_ = fmaf(X[q_].w, X[q_].w, sq_);       \
    }                                                                             \
    sum_ += __shfl_xor(sum_, 16); sum_ += __shfl_xor(sum_, 32);                   \
    sq_  += __shfl_xor(sq_, 16);  sq_  += __shfl_xor(sq_, 32);                    \
    float mu_ = sum_ * (1.f / 128.f);                                             \
    float rstd_ = rsqrtf(sq_ * (1.f / 128.f) - mu_ * mu_ + 1e-5f);                \
    f32x4 acc_ = {0.f, 0.f, 0.f, 0.f};                                            \
    _Pragma("unroll")                                                             \
    for (int ks_ = 0; ks_ < 4; ++ks_) {                                           \
      float4 u0_ = X[ks_ * 2], u1_ = X[ks_ * 2 + 1];                              \
      unsigned p0_ = cvtpk(u0_.x, u0_.y), p1_ = cvtpk(u0_.z, u0_.w);              \
      unsigned p2_ = cvtpk(u1_.x, u1_.y), p3_ = cvtpk(u1_.z, u1_.w);              \
      float l0_ = u0_.x - lo2f(p0_), l1_ = u0_.y - hi2f(p0_);                     \
      float l2_ = u0_.z - lo2f(p1_), l3_ = u0_.w - hi2f(p1_);                     \
      float l4_ = u1_.x - lo2f(p2_), l5_ = u1_.y - hi2f(p2_);                     \
      float l6_ = u1_.z - lo2f(p3_), l7_ = u1_.w - hi2f(p3_);                     \
      unsigned q0_ = cvtpk(l0_, l1_), q1_ = cvtpk(l2_, l3_);                      \
      unsigned q2_ = cvtpk(l4_, l5_), q3_ = cvtpk(l6_, l7_);                      \
      u32x4 hp_ = {p0_, p1_, p2_, p3_}, lp_ = {q0_, q1_, q2_, q3_};               \
      short8 ah_ = __builtin_bit_cast(short8, hp_);                               \
      short8 al_ = __builtin_bit_cast(short8, lp_);                               \
      acc_ = __builtin_amdgcn_mfma_f32_16x16x32_bf16(bh[ks_], ah_, acc_, 0, 0, 0);\
      acc_ = __builtin_amdgcn_mfma_f32_16x16x32_bf16(bh[ks_], al_, acc_, 0, 0, 0);\
      acc_ = __builtin_amdgcn_mfma_f32_16x16x32_bf16(bl[ks_], ah_, acc_, 0, 0, 0);\
    }                                                                             \
    _Pragma("unroll")                                                             \
    for (int r_ = 0; r_ < 4; ++r_) {                                              \
      float val_ = rstd_ * (acc_[r_] - mu_ * sgv[r_]) + bwv[r_];                  \
      lg[(kg * 4 + r_) * LGS + (CH) * 16 + l15] = val_;                           \
    }                                                                             \
  } while (0)

  PROC(Xa, wv +  0); LOADCH(Xa, wv +  8);
  PROC(Xb, wv +  4); LOADCH(Xb, wv + 12);
  PROC(Xa, wv +  8); LOADCH(Xa, wv + 16);
  PROC(Xb, wv + 12); LOADCH(Xb, wv + 20);
  PROC(Xa, wv + 16); LOADCH(Xa, wv + 24);
  PROC(Xb, wv + 20); LOADCH(Xb, wv + 28);
  PROC(Xa, wv + 24); LOADCH(Xa, wv + 32);
  PROC(Xb, wv + 28); LOADCH(Xb, wv + 36);
  PROC(Xa, wv + 32); LOADCH(Xa, wv + 40);
  PROC(Xb, wv + 36); LOADCH(Xb, wv + 44);
  PROC(Xa, wv + 40);
  PROC(Xb, wv + 44);
#undef LOADCH
#undef PROC
  __syncthreads();

#pragma unroll
  for (int hh = 0; hh < 4; ++hh) {
    int h = wv * 4 + hh;
    const float* qrow = qkl + ((size_t)n * NH + h) * NTOK;
    float x[12];
#pragma unroll
    for (int i = 0; i < 12; ++i) x[i] = lg[h * LGS + lane + 64 * i] + qrow[lane + 64 * i];
    float mx = x[0];
#pragma unroll
    for (int t = 1; t < 12; ++t) mx = fmaxf(mx, x[t]);
#pragma unroll
    for (int off = 1; off < 64; off <<= 1) mx = fmaxf(mx, __shfl_xor(mx, off));
    float e[12], sm = 0.f;
#pragma unroll
    for (int t = 0; t < 12; ++t) { e[t] = __expf(x[t] - mx); sm += e[t]; }
#pragma unroll
    for (int off = 1; off < 64; off <<= 1) sm += __shfl_xor(sm, off);
    float inv = 1.0f / sm;
    unsigned short* dst = pb + ((size_t)h * NTOK + n) * NTOK;
#pragma unroll
    for (int i = 0; i < 12; ++i) dst[lane + 64 * i] = f2bf(e[i] * inv);
  }
}

// ---------------- PV: attn*gate -> ag hi/lo bf16 (double-buffered, 1 barrier/iter) ----------------
__global__ __launch_bounds__(256) void k_pv(const unsigned short* __restrict__ wb,
                                            const unsigned short* __restrict__ vT,
                                            const float* __restrict__ gbuf,
                                            unsigned short* __restrict__ agh,
                                            unsigned short* __restrict__ agl) {
  const int ntile = blockIdx.x, h = blockIdx.y;
  const int n0 = ntile * 64;
  __shared__ unsigned short wsm[2][64 * 40];
  __shared__ unsigned short vtm[2][48 * 40];
  const int tid = threadIdx.x;
  const int wv = tid >> 6, lane = tid & 63, l15 = lane & 15, kg = lane >> 4;
  const int srow = tid >> 2, sc = tid & 3;
  const unsigned short* wsrc = wb + ((size_t)h * NTOK + (n0 + srow)) * NTOK + sc * 8;
  const unsigned short* vsrc = (tid < 192)
      ? vT + (size_t)(h * DH + srow) * NTOK + sc * 8 : nullptr;
  f32x4 acc[3];
#pragma unroll
  for (int dt = 0; dt < 3; ++dt) acc[dt] = (f32x4){0.f, 0.f, 0.f, 0.f};

  *(u16x8*)(wsm[0] + srow * 40 + sc * 8) = *(const u16x8*)(wsrc);
  if (tid < 192)
    *(u16x8*)(vtm[0] + srow * 40 + sc * 8) = *(const u16x8*)(vsrc);
  __syncthreads();

  int buf = 0;
  for (int k0 = 0; k0 < NTOK; k0 += 32) {
    if (k0 + 32 < NTOK) {
      *(u16x8*)(wsm[buf ^ 1] + srow * 40 + sc * 8) = *(const u16x8*)(wsrc + k0 + 32);
      if (tid < 192)
        *(u16x8*)(vtm[buf ^ 1] + srow * 40 + sc * 8) = *(const u16x8*)(vsrc + k0 + 32);
    }
    short8 av = *(const short8*)(wsm[buf] + (wv * 16 + l15) * 40 + kg * 8);
#pragma unroll
    for (int dt = 0; dt < 3; ++dt) {
      short8 bv = *(const short8*)(vtm[buf] + (dt * 16 + l15) * 40 + kg * 8);
      acc[dt] = __builtin_amdgcn_mfma_f32_16x16x32_bf16(av, bv, acc[dt], 0, 0, 0);
    }
    __syncthreads();
    buf ^= 1;
  }
#pragma unroll
  for (int dt = 0; dt < 3; ++dt)
#pragma unroll
    for (int r = 0; r < 4; ++r) {
      int nn = n0 + wv * 16 + kg * 4 + r;
      int col = h * DH + dt * 16 + l15;
      size_t idx = (size_t)nn * ED + col;
      float val = acc[dt][r] * gbuf[idx];
      unsigned short hb = f2bf(val);
      agh[idx] = hb;
      agl[idx] = f2bf(val - bf2f(hb));
    }
}

extern "C" void kernel_launch(void* const* d_in, const int* in_sizes, int n_in,
                              void* d_out, int out_size, void* d_ws, size_t ws_size,
                              hipStream_t stream) {
  const float* a    = (const float*)d_in[0];
  const float* s    = (const float*)d_in[1];
  const float* pair = (const float*)d_in[2];
  const float* beta = (const float*)d_in[3];
  const float* wag  = (const float*)d_in[4];
  const float* wab  = (const float*)d_in[5];
  const float* wq   = (const float*)d_in[6];
  const float* bq   = (const float*)d_in[7];
  const float* wk   = (const float*)d_in[8];
  const float* wvp  = (const float*)d_in[9];
  const float* lng  = (const float*)d_in[10];
  const float* lnb  = (const float*)d_in[11];
  const float* wpair= (const float*)d_in[12];
  const float* wg   = (const float*)d_in[13];
  const float* wproj= (const float*)d_in[14];
  const float* wo   = (const float*)d_in[15];
  const float* bo   = (const float*)d_in[16];
  float* out = (float*)d_out;

  if (ws_size < WS_NEED) return;

  char* ws = (char*)d_ws;
  unsigned short* snh  = (unsigned short*)(ws + OFF_SNH);
  unsigned short* snl  = (unsigned short*)(ws + OFF_SNL);
  unsigned short* srh  = (unsigned short*)(ws + OFF_SRH);
  unsigned short* srl  = (unsigned short*)(ws + OFF_SRL);
  float*          gaml = (float*)(ws + OFF_GAM);
  float*          betl = (float*)(ws + OFF_BET);
  float*          og   = (float*)(ws + OFF_OG);
  unsigned short* amh  = (unsigned short*)(ws + OFF_AMH);
  unsigned short* aml  = (unsigned short*)(ws + OFF_AML);
  unsigned short* qb   = (unsigned short*)(ws + OFF_QB);
  unsigned short* kb   = (unsigned short*)(ws + OFF_KB);
  unsigned short* vT   = (unsigned short*)(ws + OFF_VT);
  float*          gbuf = (float*)(ws + OFF_GBUF);
  unsigned short* agh  = (unsigned short*)(ws + OFF_AGH);
  unsigned short* agl  = (unsigned short*)(ws + OFF_AGL);
  unsigned short* wsmh = (unsigned short*)(ws + OFF_WSMH);
  unsigned short* wsml = (unsigned short*)(ws + OFF_WSML);
  unsigned short* wqh  = (unsigned short*)(ws + OFF_WQH);
  unsigned short* wql  = (unsigned short*)(ws + OFF_WQL);
  unsigned short* wph  = (unsigned short*)(ws + OFF_WPH);
  unsigned short* wpl  = (unsigned short*)(ws + OFF_WPL);
  unsigned short* gwh  = (unsigned short*)(ws + OFF_GWH);
  unsigned short* gwl  = (unsigned short*)(ws + OFF_GWL);
  float*          sgw  = (float*)(ws + OFF_SGW);
  float*          bw   = sgw + 16;
  float*          qkl  = (float*)(ws + OFF_QKL);
  unsigned short* pb   = (unsigned short*)(ws + OFF_PB);

  hipLaunchKernelGGL(k_wcvt, dim3(24, 24, 9), dim3(256), 0, stream,
                     wag, wab, wo, wq, wk, wvp, wg, wproj, lng, lnb, wpair, s,
                     wsmh, wsml, wqh, wql, wph, wpl, gwh, gwl, sgw, bw,
                     snh, snl, srh, srl);
  hipLaunchKernelGGL(k_gemm_small, dim3(36, 12), dim3(256), 0, stream,
                     snh, snl, srh, srl, wsmh, wsml, bo, gaml, betl, og);
  hipLaunchKernelGGL(k_amod, dim3(768), dim3(256), 0, stream, a, gaml, betl, amh, aml);
  hipLaunchKernelGGL(k_gemm_qkvg, dim3(48, 12), dim3(256), 0, stream,
                     amh, aml, wqh, wql, bq, qb, kb, vT, gbuf);
  hipLaunchKernelGGL(k_qkw, dim3(12, 12, 16), dim3(256), 0, stream, qb, kb, beta, qkl);
  hipLaunchKernelGGL(k_pairsm, dim3(768), dim3(256), 0, stream,
                     pair, qkl, gwh, gwl, sgw, bw, pb);
  hipLaunchKernelGGL(k_pv, dim3(12, 16), dim3(256), 0, stream, pb, vT, gbuf, agh, agl);
  hipLaunchKernelGGL(k_gemm_proj, dim3(12, 12), dim3(256), 0, stream,
                     agh, agl, wph, wpl, og, out);
}